// Round 18
// baseline (291.919 us; speedup 1.0000x reference)
//
#include <hip/hip_runtime.h>
#include <cmath>

#define D 128
#define HID 64

__device__ __forceinline__ float silu_f(float x) { return x / (1.0f + expf(-x)); }

__device__ __forceinline__ float4 fma4(float a, float4 w, float4 c) {
    c.x = fmaf(a, w.x, c.x); c.y = fmaf(a, w.y, c.y);
    c.z = fmaf(a, w.z, c.z); c.w = fmaf(a, w.w, c.w);
    return c;
}
__device__ __forceinline__ float4 silu4(float4 v) {
    v.x = silu_f(v.x); v.y = silu_f(v.y); v.z = silu_f(v.z); v.w = silu_f(v.w);
    return v;
}

// order-preserving float <-> uint encode for atomicMax on floats
__device__ __forceinline__ unsigned fenc(float f) {
    unsigned u = __float_as_uint(f);
    return (u & 0x80000000u) ? ~u : (u | 0x80000000u);
}
__device__ __forceinline__ float fdec(unsigned e) {
    unsigned u = (e & 0x80000000u) ? (e & 0x7FFFFFFFu) : ~e;
    return __uint_as_float(u);
}

#define INIT16(bp) { const float4* _b4 = reinterpret_cast<const float4*>(bp); \
    h0 = _b4[0]; h1 = _b4[1]; h2 = _b4[2]; h3 = _b4[3]; \
    h4 = _b4[4]; h5 = _b4[5]; h6 = _b4[6]; h7 = _b4[7]; \
    h8 = _b4[8]; h9 = _b4[9]; h10 = _b4[10]; h11 = _b4[11]; \
    h12 = _b4[12]; h13 = _b4[13]; h14 = _b4[14]; h15 = _b4[15]; }

#define SILU16() { h0 = silu4(h0); h1 = silu4(h1); h2 = silu4(h2); h3 = silu4(h3); \
    h4 = silu4(h4); h5 = silu4(h5); h6 = silu4(h6); h7 = silu4(h7); \
    h8 = silu4(h8); h9 = silu4(h9); h10 = silu4(h10); h11 = silu4(h11); \
    h12 = silu4(h12); h13 = silu4(h13); h14 = silu4(h14); h15 = silu4(h15); }

// dot with 4 partial sums, k%4 -> s0..s3
__device__ __forceinline__ void fd4(float4 h, float4 w, float& s0, float& s1, float& s2, float& s3) {
    s0 = fmaf(h.x, w.x, s0); s1 = fmaf(h.y, w.y, s1);
    s2 = fmaf(h.z, w.z, s2); s3 = fmaf(h.w, w.w, s3);
}
#define FD16(w4) { fd4(h0, w4[0], s0, s1, s2, s3);  fd4(h1, w4[1], s0, s1, s2, s3);  \
    fd4(h2, w4[2], s0, s1, s2, s3);  fd4(h3, w4[3], s0, s1, s2, s3);  \
    fd4(h4, w4[4], s0, s1, s2, s3);  fd4(h5, w4[5], s0, s1, s2, s3);  \
    fd4(h6, w4[6], s0, s1, s2, s3);  fd4(h7, w4[7], s0, s1, s2, s3);  \
    fd4(h8, w4[8], s0, s1, s2, s3);  fd4(h9, w4[9], s0, s1, s2, s3);  \
    fd4(h10, w4[10], s0, s1, s2, s3); fd4(h11, w4[11], s0, s1, s2, s3); \
    fd4(h12, w4[12], s0, s1, s2, s3); fd4(h13, w4[13], s0, s1, s2, s3); \
    fd4(h14, w4[14], s0, s1, s2, s3); fd4(h15, w4[15], s0, s1, s2, s3); }

// serial silu-dot over 4 units
__device__ __forceinline__ float accdot(float4 h, float4 w, float act) {
    act = fmaf(silu_f(h.x), w.x, act);
    act = fmaf(silu_f(h.y), w.y, act);
    act = fmaf(silu_f(h.z), w.z, act);
    act = fmaf(silu_f(h.w), w.w, act);
    return act;
}

// FMA dual: one weight pair (2 float4 = 8 hidden units) feeds 2 nodes
#define PDUAL(xc0, xc1, wptr) { \
    const float4* _w = reinterpret_cast<const float4*>(wptr); \
    float4 _w0 = _w[0], _w1 = _w[1]; \
    a00 = fma4(xc0, _w0, a00); a01 = fma4(xc0, _w1, a01); \
    a10 = fma4(xc1, _w0, a10); a11 = fma4(xc1, _w1, a11); }

// ---- protection net: 8-lane groups x 2 nodes, full pw1 in LDS, 64 nodes/block ----
__global__ __launch_bounds__(256) void k_protect(
    const float* __restrict__ states, const float* __restrict__ caps,
    const float* __restrict__ pw1, const float* __restrict__ pb1,
    const float* __restrict__ pw2, const float* __restrict__ pb2,
    unsigned* __restrict__ mask, unsigned* __restrict__ mlist,
    unsigned* __restrict__ counters, float* __restrict__ outmask, int N) {
    __shared__ float wl[129 * 64];                // 33 KB: all of pw1 (incl. capacity row)
    unsigned tid = threadIdx.x;
    {   // stage 2064 float4, coalesced
        const float4* s4 = reinterpret_cast<const float4*>(pw1);
        float4* d4 = reinterpret_cast<float4*>(wl);
#pragma unroll
        for (int q = 0; q < 9; ++q) {
            unsigned idx = tid + q * 256u;
            if (idx < 2064u) d4[idx] = s4[idx];
        }
    }
    __syncthreads();
    unsigned grp = tid >> 3, r = tid & 7u;        // lane r owns hidden units [r*8, r*8+8)
    unsigned nbase = blockIdx.x * 64u + grp * 2u;
    unsigned N1 = (unsigned)(N - 1);
    unsigned n0 = min(nbase + 0u, N1), n1 = min(nbase + 1u, N1);
    const float4* r0 = reinterpret_cast<const float4*>(states + (size_t)n0 * D);
    const float4* r1 = reinterpret_cast<const float4*>(states + (size_t)n1 * D);
    float4 a00, a01, a10, a11;
    { const float4* b4 = reinterpret_cast<const float4*>(pb1 + r * 8);
      a00 = b4[0]; a01 = b4[1]; a10 = a00; a11 = a01; }
    const float* wg = wl + r * 8;
#pragma unroll 2
    for (int kb = 0; kb < 32; ++kb) {
        float4 x0 = r0[kb], x1 = r1[kb];
        const float* w = wg + (size_t)kb * 256;   // kb*4 rows of 64
        PDUAL(x0.x, x1.x, w)
        PDUAL(x0.y, x1.y, w + 64)
        PDUAL(x0.z, x1.z, w + 128)
        PDUAL(x0.w, x1.w, w + 192)
    }
    {   // capacity row (input dim 128)
        float c0 = caps[n0], c1 = caps[n1];
        PDUAL(c0, c1, wg + (size_t)128 * 64)
    }
    // layer-2 partial over this lane's 8 units, then 8-lane butterfly reduce
    const float4* w2 = reinterpret_cast<const float4*>(pw2 + r * 8);
    float4 w20 = w2[0], w21 = w2[1];
    float p0 = 0.f, p1 = 0.f;
    p0 = accdot(a00, w20, p0); p0 = accdot(a01, w21, p0);
    p1 = accdot(a10, w20, p1); p1 = accdot(a11, w21, p1);
#pragma unroll
    for (int m = 1; m <= 4; m <<= 1) {
        p0 += __shfl_xor(p0, m);
        p1 += __shfl_xor(p1, m);
    }
    float pb2v = pb2[0];
    unsigned lane = tid & 63u;
#define EMIT(q, pq, nq) { \
    bool pred = false; \
    if ((nbase + q) < (unsigned)N && r == 0) { \
        float act = pq + pb2v; \
        unsigned m = (act > 0.0f) ? 1u : 0u; \
        mask[nq] = m; outmask[nq] = m ? 1.0f : 0.0f; \
        pred = (m != 0u); \
    } \
    unsigned long long bal = __ballot(pred); \
    unsigned wcnt = (unsigned)__popcll(bal); \
    unsigned pre  = (unsigned)__popcll(bal & ((1ull << lane) - 1ull)); \
    unsigned base = 0; \
    if (lane == 0 && wcnt) base = atomicAdd(&counters[1], wcnt); \
    base = __shfl(base, 0); \
    if (pred) mlist[base + pre] = nq; }
    EMIT(0, p0, n0) EMIT(1, p1, n1)
#undef EMIT
}

// ---- per-node layer-1: u[n]=W1a@x, v[n]=W1b@x; 8-lane groups x 2 nodes, 2 phases ----
__global__ __launch_bounds__(256) void k_nodemlp(
    const float* __restrict__ states, const float* __restrict__ rw1,
    float* __restrict__ u, float* __restrict__ v, int N) {
    __shared__ float wl[8192];                    // 32 KB slab
    unsigned tid = threadIdx.x;
    unsigned grp = tid >> 3, r = tid & 7u;
    unsigned nbase = blockIdx.x * 64u + grp * 2u;
    unsigned N1 = (unsigned)(N - 1);
    unsigned n0 = min(nbase + 0u, N1), n1 = min(nbase + 1u, N1);
    const float4* r0 = reinterpret_cast<const float4*>(states + (size_t)n0 * D);
    const float4* r1 = reinterpret_cast<const float4*>(states + (size_t)n1 * D);
    const float* wg = wl + r * 8;
#pragma unroll
    for (int ph = 0; ph < 2; ++ph) {
        if (ph) __syncthreads();
        {   // stage 2048 float4 (W1a or W1b)
            const float4* s4 = reinterpret_cast<const float4*>(rw1 + ph * 8192);
            float4* d4 = reinterpret_cast<float4*>(wl);
#pragma unroll
            for (int q = 0; q < 8; ++q) d4[tid + q * 256u] = s4[tid + q * 256u];
        }
        __syncthreads();
        float4 a00, a01, a10, a11;
        a00.x=a00.y=a00.z=a00.w=0.f; a01=a00; a10=a00; a11=a00;
#pragma unroll 2
        for (int kb = 0; kb < 32; ++kb) {
            float4 x0 = r0[kb], x1 = r1[kb];
            const float* w = wg + (size_t)kb * 256;
            PDUAL(x0.x, x1.x, w)
            PDUAL(x0.y, x1.y, w + 64)
            PDUAL(x0.z, x1.z, w + 128)
            PDUAL(x0.w, x1.w, w + 192)
        }
        float* dst = ph ? v : u;
        if (nbase + 0u < (unsigned)N) {
            float4* o = reinterpret_cast<float4*>(dst + (size_t)n0 * HID + r * 8);
            o[0] = a00; o[1] = a01;
        }
        if (nbase + 1u < (unsigned)N) {
            float4* o = reinterpret_cast<float4*>(dst + (size_t)n1 * HID + r * 8);
            o[0] = a10; o[1] = a11;
        }
    }
}

// compact edges with emask = mask[src] && !mask[tgt]; block-aggregated slot alloc
__global__ __launch_bounds__(256) void k_compact(
    const int* __restrict__ ei, const unsigned* __restrict__ mask,
    unsigned* __restrict__ act_eid, unsigned* __restrict__ counters,
    unsigned* __restrict__ hist, int E) {
    __shared__ unsigned wbase[4];
    int e = blockIdx.x * 256 + threadIdx.x;
    unsigned wid = threadIdx.x >> 6, lane = threadIdx.x & 63u;
    bool pred = false; int t = 0;
    if (e < E) {
        int s = ei[e]; t = ei[E + e];
        pred = mask[s] && !mask[t];
    }
    unsigned long long bal = __ballot(pred);
    unsigned wcnt = (unsigned)__popcll(bal);
    unsigned pre  = (unsigned)__popcll(bal & ((1ull << lane) - 1ull));
    if (lane == 0) wbase[wid] = wcnt;
    __syncthreads();
    if (threadIdx.x == 0) {
        unsigned c0 = wbase[0], c1 = wbase[1], c2 = wbase[2], c3 = wbase[3];
        unsigned tot = c0 + c1 + c2 + c3;
        unsigned b = tot ? atomicAdd(&counters[0], tot) : 0u;
        wbase[0] = b; wbase[1] = b + c0; wbase[2] = b + c0 + c1; wbase[3] = b + c0 + c1 + c2;
    }
    __syncthreads();
    if (pred) {
        act_eid[wbase[wid] + pre] = (unsigned)e;
        atomicAdd(&hist[t], 1u);
    }
}

// --- hierarchical exclusive scan of hist[N] -> offs[N+1], cursor[N] ---
__global__ __launch_bounds__(256) void k_scanA(const unsigned* __restrict__ hist,
                                               unsigned* __restrict__ bsum, int N) {
    __shared__ unsigned sm[256];
    unsigned t = threadIdx.x;
    unsigned i = blockIdx.x * 256u + t;
    sm[t] = (i < (unsigned)N) ? hist[i] : 0u;
    __syncthreads();
#pragma unroll
    for (unsigned d = 128; d > 0; d >>= 1) {
        if (t < d) sm[t] += sm[t + d];
        __syncthreads();
    }
    if (t == 0) bsum[blockIdx.x] = sm[0];
}
__global__ __launch_bounds__(256) void k_scanB(const unsigned* __restrict__ bsum,
                                               unsigned* __restrict__ bpre, int nb) {
    __shared__ unsigned sm[256];
    unsigned t = threadIdx.x;
    unsigned v = (t < (unsigned)nb) ? bsum[t] : 0u;
    sm[t] = v;
    __syncthreads();
    for (unsigned d = 1; d < 256; d <<= 1) {
        unsigned x = (t >= d) ? sm[t - d] : 0u;
        __syncthreads();
        sm[t] += x;
        __syncthreads();
    }
    if (t < (unsigned)nb) bpre[t] = sm[t] - v;    // exclusive
}
__global__ __launch_bounds__(256) void k_scanC(const unsigned* __restrict__ hist,
                                               const unsigned* __restrict__ bpre,
                                               unsigned* __restrict__ offs,
                                               unsigned* __restrict__ cursor, int N) {
    __shared__ unsigned sm[256];
    unsigned t = threadIdx.x;
    unsigned i = blockIdx.x * 256u + t;
    unsigned v = (i < (unsigned)N) ? hist[i] : 0u;
    sm[t] = v;
    __syncthreads();
    for (unsigned d = 1; d < 256; d <<= 1) {
        unsigned x = (t >= d) ? sm[t - d] : 0u;
        __syncthreads();
        sm[t] += x;
        __syncthreads();
    }
    unsigned exc = sm[t] - v + bpre[blockIdx.x];
    if (i < (unsigned)N) { offs[i] = exc; cursor[i] = exc; }
    if (i == (unsigned)N - 1) offs[N] = exc + v;
}

// ---- edge MLP: 2 lanes/edge split-j; h = silu(b1 + u[src] + v[tgt]); layers 2+3 ----
__global__ __launch_bounds__(256) void k_edge_mlp(
    const float* __restrict__ u, const float* __restrict__ v,
    const int* __restrict__ ei,
    const float* __restrict__ rb1, const float* __restrict__ rw2,
    const float* __restrict__ rb2, const float* __restrict__ rw3,
    const float* __restrict__ rb3,
    const unsigned* __restrict__ act_eid, const unsigned* __restrict__ counters,
    float* __restrict__ rawbuf, unsigned* __restrict__ segmax, int E) {
    __shared__ float w2t[64 * 68];                // rw2 transposed, padded stride
    unsigned cnt = counters[0];
    if (blockIdx.x * 128u >= cnt) return;         // whole block inactive (uniform)
    unsigned tid = threadIdx.x;
#pragma unroll
    for (int q = 0; q < 16; ++q) {
        int i = (int)tid + q * 256;
        w2t[(i & 63) * 68 + (i >> 6)] = rw2[i];
    }
    __syncthreads();
    unsigned grp = blockIdx.x * 128u + (tid >> 1);
    unsigned p = tid & 1u;
    bool active = grp < cnt;
    unsigned gq = active ? grp : (cnt - 1);
    int e = (int)act_eid[gq];
    int s = ei[e], tg = ei[E + e];
    const float4* ur = reinterpret_cast<const float4*>(u + (size_t)s * HID);
    const float4* vr = reinterpret_cast<const float4*>(v + (size_t)tg * HID);
    float4 h0, h1, h2, h3, h4, h5, h6, h7, h8, h9, h10, h11, h12, h13, h14, h15;
    INIT16(rb1);
#define ADDUV(hh, i) { float4 _u = ur[i]; float4 _v = vr[i]; \
    hh.x = hh.x + _u.x + _v.x; hh.y = hh.y + _u.y + _v.y; \
    hh.z = hh.z + _u.z + _v.z; hh.w = hh.w + _u.w + _v.w; }
    ADDUV(h0, 0)  ADDUV(h1, 1)  ADDUV(h2, 2)  ADDUV(h3, 3)
    ADDUV(h4, 4)  ADDUV(h5, 5)  ADDUV(h6, 6)  ADDUV(h7, 7)
    ADDUV(h8, 8)  ADDUV(h9, 9)  ADDUV(h10, 10) ADDUV(h11, 11)
    ADDUV(h12, 12) ADDUV(h13, 13) ADDUV(h14, 14) ADDUV(h15, 15)
#undef ADDUV
    SILU16();
    // layers 2+3: lane p handles j in [32p, 32p+32), then pair-reduce
    float part = 0.0f;
    int j0 = 32 * (int)p;
#pragma unroll 1
    for (int j = j0; j < j0 + 32; ++j) {
        const float4* w4 = reinterpret_cast<const float4*>(w2t + j * 68);
        float s0 = rb2[j], s1 = 0.f, s2 = 0.f, s3 = 0.f;
        FD16(w4);
        float h2v = silu_f((s0 + s1) + (s2 + s3));
        part = fmaf(h2v, rw3[j], part);
    }
    part += __shfl_xor(part, 1);
    if (active && p == 0) {
        float raw = part + rb3[0];
        rawbuf[grp] = raw;
        atomicMax(&segmax[s], fenc(raw));
    }
}

__global__ void k_exp(const int* __restrict__ ei, const unsigned* __restrict__ act_eid,
                      const unsigned* __restrict__ counters, const unsigned* __restrict__ segmax,
                      float* __restrict__ rawbuf, float* __restrict__ denom, int E) {
    unsigned t = blockIdx.x * blockDim.x + threadIdx.x;
    if (blockIdx.x * blockDim.x >= counters[0]) return;
    if (t >= counters[0]) return;
    int e = (int)act_eid[t];
    int s = ei[e];
    float ev = expf(rawbuf[t] - fdec(segmax[s]));
    rawbuf[t] = ev;
    atomicAdd(&denom[s], ev);
}

// bucket by target with final weight + src pre-packed (coalesced streams for gather)
__global__ void k_fill(const int* __restrict__ ei, const unsigned* __restrict__ act_eid,
                       const unsigned* __restrict__ counters, const float* __restrict__ rawbuf,
                       const float* __restrict__ denom, unsigned* __restrict__ cursor,
                       float* __restrict__ wbuf, unsigned* __restrict__ sbuf, int E) {
    unsigned t = blockIdx.x * blockDim.x + threadIdx.x;
    if (blockIdx.x * blockDim.x >= counters[0]) return;
    if (t >= counters[0]) return;
    int e = (int)act_eid[t];
    int s = ei[e], tg = ei[E + e];
    float w = rawbuf[t] / denom[s];
    unsigned pos = atomicAdd(&cursor[tg], 1u);
    wbuf[pos] = w;
    sbuf[pos] = (unsigned)s;
}

// wave per node: out[n] = states[n] + sum_{incoming active} w * states[src]
__global__ __launch_bounds__(256) void k_gather(
    const float* __restrict__ states, const float* __restrict__ wbuf,
    const unsigned* __restrict__ sbuf, const unsigned* __restrict__ offs,
    float* __restrict__ out, int N) {
    unsigned n = blockIdx.x * 4u + (threadIdx.x >> 6);
    unsigned lane = threadIdx.x & 63u;
    if (n >= (unsigned)N) return;
    unsigned start = offs[n], end = offs[n + 1];
    float2 acc = reinterpret_cast<const float2*>(states + (size_t)n * D)[lane];
    for (unsigned i = start; i < end; ++i) {
        float w = wbuf[i];
        unsigned s = sbuf[i];
        float2 sv = reinterpret_cast<const float2*>(states + (size_t)s * D)[lane];
        acc.x = fmaf(w, sv.x, acc.x);
        acc.y = fmaf(w, sv.y, acc.y);
    }
    reinterpret_cast<float2*>(out + (size_t)n * D)[lane] = acc;
}

// failed nodes: out = tanh(states @ tw + tb) * 0.05
__global__ __launch_bounds__(256) void k_jump(
    const float* __restrict__ states,
    const float* __restrict__ tw, const float* __restrict__ tb,
    const unsigned* __restrict__ mlist, const unsigned* __restrict__ counters,
    float* __restrict__ out) {
    __shared__ float xs[8][D];
    unsigned cnt = counters[1];
    unsigned base = blockIdx.x * 8u;
    if (base >= cnt || cnt == 0) return;          // uniform
    unsigned tid = threadIdx.x;
    unsigned d = tid & 127u, r = tid >> 7;        // r in {0,1}
    {   // stage 8 rows (clamped): 32 threads per row, float4 each
        unsigned j = tid >> 5;
        unsigned c = (tid & 31u) * 4u;
        unsigned slot = base + j; if (slot >= cnt) slot = cnt - 1;
        int nn = (int)mlist[slot];
        *reinterpret_cast<float4*>(&xs[j][c]) =
            *reinterpret_cast<const float4*>(&states[(size_t)nn * D + c]);
    }
    __syncthreads();
    float tbd = tb[d];
    float a0 = tbd, a1 = tbd, a2 = tbd, a3 = tbd;
    const float* x0 = &xs[r * 4 + 0][0];
    const float* x1 = &xs[r * 4 + 1][0];
    const float* x2 = &xs[r * 4 + 2][0];
    const float* x3 = &xs[r * 4 + 3][0];
#pragma unroll 1
    for (int k = 0; k < D; ++k) {
        float w = tw[(size_t)k * D + d];
        a0 = fmaf(x0[k], w, a0);
        a1 = fmaf(x1[k], w, a1);
        a2 = fmaf(x2[k], w, a2);
        a3 = fmaf(x3[k], w, a3);
    }
    float res[4] = {a0, a1, a2, a3};
#pragma unroll
    for (int j2 = 0; j2 < 4; ++j2) {
        unsigned slot = base + r * 4 + j2;
        if (slot < cnt) {
            int nn = (int)mlist[slot];
            out[(size_t)nn * D + d] = tanhf(res[j2]) * 0.05f;
        }
    }
}

extern "C" void kernel_launch(void* const* d_in, const int* in_sizes, int n_in,
                              void* d_out, int out_size, void* d_ws, size_t ws_size,
                              hipStream_t stream) {
    const float* states = (const float*)d_in[0];
    const float* caps   = (const float*)d_in[1];
    const int*   ei     = (const int*)d_in[2];
    const float* rw1 = (const float*)d_in[3];  const float* rb1 = (const float*)d_in[4];
    const float* rw2 = (const float*)d_in[5];  const float* rb2 = (const float*)d_in[6];
    const float* rw3 = (const float*)d_in[7];  const float* rb3 = (const float*)d_in[8];
    const float* pw1 = (const float*)d_in[9];  const float* pb1 = (const float*)d_in[10];
    const float* pw2 = (const float*)d_in[11]; const float* pb2 = (const float*)d_in[12];
    const float* tw  = (const float*)d_in[13]; const float* tb  = (const float*)d_in[14];
    const int N = in_sizes[1];
    const int E = in_sizes[2] / 2;
    float* out = (float*)d_out;
    const int nb = (N + 255) / 256;

    // u,v live in d_out[0 : 2*N*HID) = d_out[0 : N*D) — dead scratch until k_gather.
    float* u = out;
    float* v = out + (size_t)N * HID;

    // ws layout (u32 units):
    // [0..3] counters | segmax N | denom N | hist N | mask N | mlist N |
    // offs N+1 | cursor N | bsum 256 | bpre 256 | act_eid E | rawbuf E | wbuf E | sbuf E
    unsigned* ws       = (unsigned*)d_ws;
    unsigned* counters = ws;
    unsigned* segmax   = ws + 4;
    float*    denom    = (float*)(ws + 4 + 1 * (size_t)N);
    unsigned* hist     = ws + 4 + 2 * (size_t)N;
    unsigned* mask     = ws + 4 + 3 * (size_t)N;
    unsigned* mlist    = ws + 4 + 4 * (size_t)N;
    unsigned* offs     = ws + 4 + 5 * (size_t)N;
    unsigned* cursor   = ws + 4 + 6 * (size_t)N + 1;
    unsigned* bsum     = ws + 4 + 7 * (size_t)N + 1;
    unsigned* bpre     = bsum + 256;
    unsigned* act_eid  = bpre + 256;
    float*    rawbuf   = (float*)(act_eid + (size_t)E);
    float*    wbuf     = (float*)(act_eid + 2 * (size_t)E);
    unsigned* sbuf     = act_eid + 3 * (size_t)E;

    // zero counters + segmax + denom + hist (contiguous prefix)
    (void)hipMemsetAsync(d_ws, 0, (size_t)(4 + 3 * (size_t)N) * 4, stream);

    k_protect<<<(N + 63) / 64, 256, 0, stream>>>(states, caps, pw1, pb1, pw2, pb2,
                                                 mask, mlist, counters, out + (size_t)N * D, N);
    k_nodemlp<<<(N + 63) / 64, 256, 0, stream>>>(states, rw1, u, v, N);
    k_compact<<<(E + 255) / 256, 256, 0, stream>>>(ei, mask, act_eid, counters, hist, E);
    k_scanA<<<nb, 256, 0, stream>>>(hist, bsum, N);
    k_scanB<<<1, 256, 0, stream>>>(bsum, bpre, nb);
    k_scanC<<<nb, 256, 0, stream>>>(hist, bpre, offs, cursor, N);
    k_edge_mlp<<<(2 * E + 255) / 256, 256, 0, stream>>>(u, v, ei, rb1, rw2, rb2, rw3, rb3,
                                                        act_eid, counters, rawbuf, segmax, E);
    k_exp<<<(E + 255) / 256, 256, 0, stream>>>(ei, act_eid, counters, segmax, rawbuf, denom, E);
    k_fill<<<(E + 255) / 256, 256, 0, stream>>>(ei, act_eid, counters, rawbuf, denom,
                                                cursor, wbuf, sbuf, E);
    k_gather<<<(N + 3) / 4, 256, 0, stream>>>(states, wbuf, sbuf, offs, out, N);
    k_jump<<<(N + 7) / 8, 256, 0, stream>>>(states, tw, tb, mlist, counters, out);
}

// Round 19
// 266.409 us; speedup vs baseline: 1.0958x; 1.0958x over previous
//
#include <hip/hip_runtime.h>
#include <cmath>

#define D 128
#define HID 64

__device__ __forceinline__ float silu_f(float x) { return x / (1.0f + expf(-x)); }

__device__ __forceinline__ float4 fma4(float a, float4 w, float4 c) {
    c.x = fmaf(a, w.x, c.x); c.y = fmaf(a, w.y, c.y);
    c.z = fmaf(a, w.z, c.z); c.w = fmaf(a, w.w, c.w);
    return c;
}
__device__ __forceinline__ float4 silu4(float4 v) {
    v.x = silu_f(v.x); v.y = silu_f(v.y); v.z = silu_f(v.z); v.w = silu_f(v.w);
    return v;
}

// order-preserving float <-> uint encode for atomicMax on floats
__device__ __forceinline__ unsigned fenc(float f) {
    unsigned u = __float_as_uint(f);
    return (u & 0x80000000u) ? ~u : (u | 0x80000000u);
}
__device__ __forceinline__ float fdec(unsigned e) {
    unsigned u = (e & 0x80000000u) ? (e & 0x7FFFFFFFu) : ~e;
    return __uint_as_float(u);
}

#define INIT16(bp) { const float4* _b4 = reinterpret_cast<const float4*>(bp); \
    h0 = _b4[0]; h1 = _b4[1]; h2 = _b4[2]; h3 = _b4[3]; \
    h4 = _b4[4]; h5 = _b4[5]; h6 = _b4[6]; h7 = _b4[7]; \
    h8 = _b4[8]; h9 = _b4[9]; h10 = _b4[10]; h11 = _b4[11]; \
    h12 = _b4[12]; h13 = _b4[13]; h14 = _b4[14]; h15 = _b4[15]; }

#define SILU16() { h0 = silu4(h0); h1 = silu4(h1); h2 = silu4(h2); h3 = silu4(h3); \
    h4 = silu4(h4); h5 = silu4(h5); h6 = silu4(h6); h7 = silu4(h7); \
    h8 = silu4(h8); h9 = silu4(h9); h10 = silu4(h10); h11 = silu4(h11); \
    h12 = silu4(h12); h13 = silu4(h13); h14 = silu4(h14); h15 = silu4(h15); }

// dot with 4 partial sums, k%4 -> s0..s3
__device__ __forceinline__ void fd4(float4 h, float4 w, float& s0, float& s1, float& s2, float& s3) {
    s0 = fmaf(h.x, w.x, s0); s1 = fmaf(h.y, w.y, s1);
    s2 = fmaf(h.z, w.z, s2); s3 = fmaf(h.w, w.w, s3);
}
#define FD16(w4) { fd4(h0, w4[0], s0, s1, s2, s3);  fd4(h1, w4[1], s0, s1, s2, s3);  \
    fd4(h2, w4[2], s0, s1, s2, s3);  fd4(h3, w4[3], s0, s1, s2, s3);  \
    fd4(h4, w4[4], s0, s1, s2, s3);  fd4(h5, w4[5], s0, s1, s2, s3);  \
    fd4(h6, w4[6], s0, s1, s2, s3);  fd4(h7, w4[7], s0, s1, s2, s3);  \
    fd4(h8, w4[8], s0, s1, s2, s3);  fd4(h9, w4[9], s0, s1, s2, s3);  \
    fd4(h10, w4[10], s0, s1, s2, s3); fd4(h11, w4[11], s0, s1, s2, s3); \
    fd4(h12, w4[12], s0, s1, s2, s3); fd4(h13, w4[13], s0, s1, s2, s3); \
    fd4(h14, w4[14], s0, s1, s2, s3); fd4(h15, w4[15], s0, s1, s2, s3); }

// serial silu-dot over 4 units
__device__ __forceinline__ float accdot(float4 h, float4 w, float act) {
    act = fmaf(silu_f(h.x), w.x, act);
    act = fmaf(silu_f(h.y), w.y, act);
    act = fmaf(silu_f(h.z), w.z, act);
    act = fmaf(silu_f(h.w), w.w, act);
    return act;
}

// transpose rw2 (64x64) -> rw2T[j*64+k] = rw2[k*64+j]  (uniform contiguous rows per j)
__global__ void k_prep(const float* __restrict__ rw2, float* __restrict__ rw2T) {
    int i = blockIdx.x * blockDim.x + threadIdx.x;
    if (i < HID * HID) rw2T[i] = rw2[(i & (HID - 1)) * HID + (i >> 6)];
}

// ---- protection net: 4 lanes/node split-hid, full pw1 in LDS, 64 nodes/block (r12) ----
__global__ __launch_bounds__(256) void k_protect(
    const float* __restrict__ states, const float* __restrict__ caps,
    const float* __restrict__ pw1, const float* __restrict__ pb1,
    const float* __restrict__ pw2, const float* __restrict__ pb2,
    unsigned* __restrict__ mask, unsigned* __restrict__ mlist,
    unsigned* __restrict__ counters, float* __restrict__ outmask, int N) {
    __shared__ float wl[129 * 64];                // 33 KB: all of pw1 (incl. capacity row)
    unsigned tid = threadIdx.x;
    {   // stage 8256 floats = 2064 float4, coalesced
        const float4* s4 = reinterpret_cast<const float4*>(pw1);
        float4* d4 = reinterpret_cast<float4*>(wl);
#pragma unroll
        for (int q = 0; q < 9; ++q) {
            unsigned idx = tid + q * 256u;
            if (idx < 2064u) d4[idx] = s4[idx];
        }
    }
    __syncthreads();
    unsigned nl = tid >> 2, g = tid & 3u;         // lane g owns hidden units [g*16, g*16+16)
    unsigned n = blockIdx.x * 64u + nl;
    bool active = n < (unsigned)N;
    unsigned nq = active ? n : (unsigned)(N - 1);
    const float4* row = reinterpret_cast<const float4*>(states + (size_t)nq * D);
    float4 a0, a1, a2, a3;
    { const float4* b4 = reinterpret_cast<const float4*>(pb1 + g * 16);
      a0 = b4[0]; a1 = b4[1]; a2 = b4[2]; a3 = b4[3]; }
    const float* wg = wl + g * 16;
#pragma unroll 1
    for (int kb = 0; kb < 32; ++kb) {
        float4 x = row[kb];
        const float* w = wg + (size_t)kb * 4 * HID;
        const float4* w0 = reinterpret_cast<const float4*>(w);
        const float4* w1 = reinterpret_cast<const float4*>(w + HID);
        const float4* w2q = reinterpret_cast<const float4*>(w + 2 * HID);
        const float4* w3q = reinterpret_cast<const float4*>(w + 3 * HID);
        a0 = fma4(x.x, w0[0], a0); a1 = fma4(x.x, w0[1], a1); a2 = fma4(x.x, w0[2], a2); a3 = fma4(x.x, w0[3], a3);
        a0 = fma4(x.y, w1[0], a0); a1 = fma4(x.y, w1[1], a1); a2 = fma4(x.y, w1[2], a2); a3 = fma4(x.y, w1[3], a3);
        a0 = fma4(x.z, w2q[0], a0); a1 = fma4(x.z, w2q[1], a1); a2 = fma4(x.z, w2q[2], a2); a3 = fma4(x.z, w2q[3], a3);
        a0 = fma4(x.w, w3q[0], a0); a1 = fma4(x.w, w3q[1], a1); a2 = fma4(x.w, w3q[2], a2); a3 = fma4(x.w, w3q[3], a3);
    }
    {   // capacity row (input dim 128)
        float xv = caps[nq];
        const float4* wc = reinterpret_cast<const float4*>(wg + (size_t)128 * HID);
        a0 = fma4(xv, wc[0], a0); a1 = fma4(xv, wc[1], a1);
        a2 = fma4(xv, wc[2], a2); a3 = fma4(xv, wc[3], a3);
    }
    // layer-2 partial over this lane's 16 units, then 4-lane butterfly reduce
    const float4* w2 = reinterpret_cast<const float4*>(pw2 + g * 16);
    float p = 0.0f;
    p = accdot(a0, w2[0], p); p = accdot(a1, w2[1], p);
    p = accdot(a2, w2[2], p); p = accdot(a3, w2[3], p);
    p += __shfl_xor(p, 1);
    p += __shfl_xor(p, 2);
    // mask decision + wave-aggregated append to mlist (one atomic per wave)
    bool pred = false;
    if (active && g == 0) {
        float act = p + pb2[0];
        unsigned m = (act > 0.0f) ? 1u : 0u;
        mask[n] = m;
        outmask[n] = m ? 1.0f : 0.0f;
        pred = (m != 0u);
    }
    unsigned lane = tid & 63u;
    unsigned long long bal = __ballot(pred);
    unsigned wcnt = (unsigned)__popcll(bal);
    unsigned pre  = (unsigned)__popcll(bal & ((1ull << lane) - 1ull));
    unsigned base = 0;
    if (lane == 0 && wcnt) base = atomicAdd(&counters[1], wcnt);
    base = __shfl(base, 0);
    if (pred) mlist[base + pre] = n;
}

// ---- per-node layer-1 factorization: uv[n] = (mask ? W1a : W1b) @ states[n] (r12) ----
__global__ __launch_bounds__(256) void k_nodemlp(
    const float* __restrict__ states, const unsigned* __restrict__ mask,
    const float* __restrict__ rw1, float* __restrict__ uv, int N) {
    __shared__ float wl[16384];                   // 64 KB: W1a (8192) | W1b (8192)
    unsigned tid = threadIdx.x;
    {   // stage all of rw1: 4096 float4, coalesced
        const float4* s4 = reinterpret_cast<const float4*>(rw1);
        float4* d4 = reinterpret_cast<float4*>(wl);
#pragma unroll
        for (int q = 0; q < 16; ++q) d4[tid + q * 256u] = s4[tid + q * 256u];
    }
    __syncthreads();
    unsigned nl = tid >> 2, g = tid & 3u;
    unsigned n = blockIdx.x * 64u + nl;
    if (n >= (unsigned)N) return;
    const float4* row = reinterpret_cast<const float4*>(states + (size_t)n * D);
    unsigned m = mask[n];
    const float* wg = wl + (m ? 0u : 8192u) + g * 16;
    float4 a0, a1, a2, a3;
    a0.x=a0.y=a0.z=a0.w=0.f; a1=a0; a2=a0; a3=a0;
#pragma unroll 1
    for (int kb = 0; kb < 32; ++kb) {
        float4 x = row[kb];
        const float* w = wg + (size_t)kb * 4 * HID;
        const float4* w0 = reinterpret_cast<const float4*>(w);
        const float4* w1 = reinterpret_cast<const float4*>(w + HID);
        const float4* w2q = reinterpret_cast<const float4*>(w + 2 * HID);
        const float4* w3q = reinterpret_cast<const float4*>(w + 3 * HID);
        a0 = fma4(x.x, w0[0], a0); a1 = fma4(x.x, w0[1], a1); a2 = fma4(x.x, w0[2], a2); a3 = fma4(x.x, w0[3], a3);
        a0 = fma4(x.y, w1[0], a0); a1 = fma4(x.y, w1[1], a1); a2 = fma4(x.y, w1[2], a2); a3 = fma4(x.y, w1[3], a3);
        a0 = fma4(x.z, w2q[0], a0); a1 = fma4(x.z, w2q[1], a1); a2 = fma4(x.z, w2q[2], a2); a3 = fma4(x.z, w2q[3], a3);
        a0 = fma4(x.w, w3q[0], a0); a1 = fma4(x.w, w3q[1], a1); a2 = fma4(x.w, w3q[2], a2); a3 = fma4(x.w, w3q[3], a3);
    }
    float4* o = reinterpret_cast<float4*>(uv + (size_t)n * HID + g * 16);
    o[0] = a0; o[1] = a1; o[2] = a2; o[3] = a3;
}

// compact edges with emask = mask[src] && !mask[tgt]; block-aggregated slot alloc
__global__ __launch_bounds__(256) void k_compact(
    const int* __restrict__ ei, const unsigned* __restrict__ mask,
    unsigned* __restrict__ act_eid, unsigned* __restrict__ counters,
    unsigned* __restrict__ hist, int E) {
    __shared__ unsigned wbase[4];
    int e = blockIdx.x * 256 + threadIdx.x;
    unsigned wid = threadIdx.x >> 6, lane = threadIdx.x & 63u;
    bool pred = false; int t = 0;
    if (e < E) {
        int s = ei[e]; t = ei[E + e];
        pred = mask[s] && !mask[t];
    }
    unsigned long long bal = __ballot(pred);
    unsigned wcnt = (unsigned)__popcll(bal);
    unsigned pre  = (unsigned)__popcll(bal & ((1ull << lane) - 1ull));
    if (lane == 0) wbase[wid] = wcnt;
    __syncthreads();
    if (threadIdx.x == 0) {
        unsigned c0 = wbase[0], c1 = wbase[1], c2 = wbase[2], c3 = wbase[3];
        unsigned tot = c0 + c1 + c2 + c3;
        unsigned b = tot ? atomicAdd(&counters[0], tot) : 0u;
        wbase[0] = b; wbase[1] = b + c0; wbase[2] = b + c0 + c1; wbase[3] = b + c0 + c1 + c2;
    }
    __syncthreads();
    if (pred) {
        act_eid[wbase[wid] + pre] = (unsigned)e;
        atomicAdd(&hist[t], 1u);
    }
}

// --- hierarchical exclusive scan of hist[N] -> offs[N+1], cursor[N] ---
__global__ __launch_bounds__(256) void k_scanA(const unsigned* __restrict__ hist,
                                               unsigned* __restrict__ bsum, int N) {
    __shared__ unsigned sm[256];
    unsigned t = threadIdx.x;
    unsigned i = blockIdx.x * 256u + t;
    sm[t] = (i < (unsigned)N) ? hist[i] : 0u;
    __syncthreads();
#pragma unroll
    for (unsigned d = 128; d > 0; d >>= 1) {
        if (t < d) sm[t] += sm[t + d];
        __syncthreads();
    }
    if (t == 0) bsum[blockIdx.x] = sm[0];
}
__global__ __launch_bounds__(256) void k_scanB(const unsigned* __restrict__ bsum,
                                               unsigned* __restrict__ bpre, int nb) {
    __shared__ unsigned sm[256];
    unsigned t = threadIdx.x;
    unsigned v = (t < (unsigned)nb) ? bsum[t] : 0u;
    sm[t] = v;
    __syncthreads();
    for (unsigned d = 1; d < 256; d <<= 1) {
        unsigned x = (t >= d) ? sm[t - d] : 0u;
        __syncthreads();
        sm[t] += x;
        __syncthreads();
    }
    if (t < (unsigned)nb) bpre[t] = sm[t] - v;    // exclusive
}
__global__ __launch_bounds__(256) void k_scanC(const unsigned* __restrict__ hist,
                                               const unsigned* __restrict__ bpre,
                                               unsigned* __restrict__ offs,
                                               unsigned* __restrict__ cursor, int N) {
    __shared__ unsigned sm[256];
    unsigned t = threadIdx.x;
    unsigned i = blockIdx.x * 256u + t;
    unsigned v = (i < (unsigned)N) ? hist[i] : 0u;
    sm[t] = v;
    __syncthreads();
    for (unsigned d = 1; d < 256; d <<= 1) {
        unsigned x = (t >= d) ? sm[t - d] : 0u;
        __syncthreads();
        sm[t] += x;
        __syncthreads();
    }
    unsigned exc = sm[t] - v + bpre[blockIdx.x];
    if (i < (unsigned)N) { offs[i] = exc; cursor[i] = exc; }
    if (i == (unsigned)N - 1) offs[N] = exc + v;
}

// ---- edge MLP: h = silu(b1 + uv[src] + uv[tgt]); layers 2+3 from GLOBAL rw2T ----
// weight reads are wave-uniform -> scalar-cached; no LDS, no barrier.
__global__ __launch_bounds__(256) void k_edge_mlp(
    const float* __restrict__ uv, const int* __restrict__ ei,
    const float* __restrict__ rb1, const float* __restrict__ rw2T,
    const float* __restrict__ rb2, const float* __restrict__ rw3,
    const float* __restrict__ rb3,
    const unsigned* __restrict__ act_eid, const unsigned* __restrict__ counters,
    float* __restrict__ rawbuf, unsigned* __restrict__ segmax, int E) {
    unsigned cnt = counters[0];
    if (blockIdx.x * 256u >= cnt) return;         // whole block inactive (uniform)
    unsigned tid = threadIdx.x;
    unsigned grp = blockIdx.x * 256u + tid;
    bool active = grp < cnt;
    unsigned gq = active ? grp : (cnt - 1);
    int e = (int)act_eid[gq];
    int s = ei[e], tg = ei[E + e];
    const float4* ur = reinterpret_cast<const float4*>(uv + (size_t)s * HID);
    const float4* vr = reinterpret_cast<const float4*>(uv + (size_t)tg * HID);
    float4 h0, h1, h2, h3, h4, h5, h6, h7, h8, h9, h10, h11, h12, h13, h14, h15;
    INIT16(rb1);
#define ADDUV(hh, i) { float4 _u = ur[i]; float4 _v = vr[i]; \
    hh.x = hh.x + _u.x + _v.x; hh.y = hh.y + _u.y + _v.y; \
    hh.z = hh.z + _u.z + _v.z; hh.w = hh.w + _u.w + _v.w; }
    ADDUV(h0, 0)  ADDUV(h1, 1)  ADDUV(h2, 2)  ADDUV(h3, 3)
    ADDUV(h4, 4)  ADDUV(h5, 5)  ADDUV(h6, 6)  ADDUV(h7, 7)
    ADDUV(h8, 8)  ADDUV(h9, 9)  ADDUV(h10, 10) ADDUV(h11, 11)
    ADDUV(h12, 12) ADDUV(h13, 13) ADDUV(h14, 14) ADDUV(h15, 15)
#undef ADDUV
    SILU16();
    // layers 2+3 fused: per j, dot(h, rw2T[j]) -> silu -> raw += h2*rw3[j]
    float raw = rb3[0];
#pragma unroll 1
    for (int j = 0; j < HID; ++j) {
        const float4* w4 = reinterpret_cast<const float4*>(rw2T + (size_t)j * HID);
        float s0 = rb2[j], s1 = 0.f, s2 = 0.f, s3 = 0.f;
        FD16(w4);
        float h2v = silu_f((s0 + s1) + (s2 + s3));
        raw = fmaf(h2v, rw3[j], raw);
    }
    if (active) {
        rawbuf[grp] = raw;
        atomicMax(&segmax[s], fenc(raw));
    }
}

__global__ void k_exp(const int* __restrict__ ei, const unsigned* __restrict__ act_eid,
                      const unsigned* __restrict__ counters, const unsigned* __restrict__ segmax,
                      float* __restrict__ rawbuf, float* __restrict__ denom, int E) {
    unsigned t = blockIdx.x * blockDim.x + threadIdx.x;
    if (blockIdx.x * blockDim.x >= counters[0]) return;
    if (t >= counters[0]) return;
    int e = (int)act_eid[t];
    int s = ei[e];
    float ev = expf(rawbuf[t] - fdec(segmax[s]));
    rawbuf[t] = ev;
    atomicAdd(&denom[s], ev);
}

// bucket by target with final weight + src pre-packed (coalesced streams for gather)
__global__ void k_fill(const int* __restrict__ ei, const unsigned* __restrict__ act_eid,
                       const unsigned* __restrict__ counters, const float* __restrict__ rawbuf,
                       const float* __restrict__ denom, unsigned* __restrict__ cursor,
                       float* __restrict__ wbuf, unsigned* __restrict__ sbuf, int E) {
    unsigned t = blockIdx.x * blockDim.x + threadIdx.x;
    if (blockIdx.x * blockDim.x >= counters[0]) return;
    if (t >= counters[0]) return;
    int e = (int)act_eid[t];
    int s = ei[e], tg = ei[E + e];
    float w = rawbuf[t] / denom[s];
    unsigned pos = atomicAdd(&cursor[tg], 1u);
    wbuf[pos] = w;
    sbuf[pos] = (unsigned)s;
}

// wave per node: out[n] = states[n] + sum_{incoming active} w * states[src]
// masked nodes skipped entirely (k_jump overwrites them; they receive no messages)
__global__ __launch_bounds__(256) void k_gather(
    const float* __restrict__ states, const float* __restrict__ wbuf,
    const unsigned* __restrict__ sbuf, const unsigned* __restrict__ offs,
    const unsigned* __restrict__ mask, float* __restrict__ out, int N) {
    unsigned n = blockIdx.x * 4u + (threadIdx.x >> 6);
    unsigned lane = threadIdx.x & 63u;
    if (n >= (unsigned)N) return;
    if (mask[n]) return;                          // overwritten by k_jump
    unsigned start = offs[n], end = offs[n + 1];
    float2 acc = reinterpret_cast<const float2*>(states + (size_t)n * D)[lane];
    for (unsigned i = start; i < end; ++i) {
        float w = wbuf[i];
        unsigned s = sbuf[i];
        float2 sv = reinterpret_cast<const float2*>(states + (size_t)s * D)[lane];
        acc.x = fmaf(w, sv.x, acc.x);
        acc.y = fmaf(w, sv.y, acc.y);
    }
    reinterpret_cast<float2*>(out + (size_t)n * D)[lane] = acc;
}

// failed nodes: out = tanh(states @ tw + tb) * 0.05
__global__ __launch_bounds__(256) void k_jump(
    const float* __restrict__ states,
    const float* __restrict__ tw, const float* __restrict__ tb,
    const unsigned* __restrict__ mlist, const unsigned* __restrict__ counters,
    float* __restrict__ out) {
    __shared__ float xs[8][D];
    unsigned cnt = counters[1];
    unsigned base = blockIdx.x * 8u;
    if (base >= cnt || cnt == 0) return;          // uniform
    unsigned tid = threadIdx.x;
    unsigned d = tid & 127u, r = tid >> 7;        // r in {0,1}
    {   // stage 8 rows (clamped): 32 threads per row, float4 each
        unsigned j = tid >> 5;
        unsigned c = (tid & 31u) * 4u;
        unsigned slot = base + j; if (slot >= cnt) slot = cnt - 1;
        int nn = (int)mlist[slot];
        *reinterpret_cast<float4*>(&xs[j][c]) =
            *reinterpret_cast<const float4*>(&states[(size_t)nn * D + c]);
    }
    __syncthreads();
    float tbd = tb[d];
    float a0 = tbd, a1 = tbd, a2 = tbd, a3 = tbd;
    const float* x0 = &xs[r * 4 + 0][0];
    const float* x1 = &xs[r * 4 + 1][0];
    const float* x2 = &xs[r * 4 + 2][0];
    const float* x3 = &xs[r * 4 + 3][0];
#pragma unroll 1
    for (int k = 0; k < D; ++k) {
        float w = tw[(size_t)k * D + d];
        a0 = fmaf(x0[k], w, a0);
        a1 = fmaf(x1[k], w, a1);
        a2 = fmaf(x2[k], w, a2);
        a3 = fmaf(x3[k], w, a3);
    }
    float res[4] = {a0, a1, a2, a3};
#pragma unroll
    for (int j2 = 0; j2 < 4; ++j2) {
        unsigned slot = base + r * 4 + j2;
        if (slot < cnt) {
            int nn = (int)mlist[slot];
            out[(size_t)nn * D + d] = tanhf(res[j2]) * 0.05f;
        }
    }
}

extern "C" void kernel_launch(void* const* d_in, const int* in_sizes, int n_in,
                              void* d_out, int out_size, void* d_ws, size_t ws_size,
                              hipStream_t stream) {
    const float* states = (const float*)d_in[0];
    const float* caps   = (const float*)d_in[1];
    const int*   ei     = (const int*)d_in[2];
    const float* rw1 = (const float*)d_in[3];  const float* rb1 = (const float*)d_in[4];
    const float* rw2 = (const float*)d_in[5];  const float* rb2 = (const float*)d_in[6];
    const float* rw3 = (const float*)d_in[7];  const float* rb3 = (const float*)d_in[8];
    const float* pw1 = (const float*)d_in[9];  const float* pb1 = (const float*)d_in[10];
    const float* pw2 = (const float*)d_in[11]; const float* pb2 = (const float*)d_in[12];
    const float* tw  = (const float*)d_in[13]; const float* tb  = (const float*)d_in[14];
    const int N = in_sizes[1];
    const int E = in_sizes[2] / 2;
    float* out = (float*)d_out;
    const int nb = (N + 255) / 256;

    // uv lives in d_out[0 : N*HID) — dead scratch until k_gather/k_jump write out.
    float* uv = out;

    // ws layout (u32 units):
    // [0..3] counters | segmax N | denom N | hist N | mask N | mlist N |
    // offs N+1 | cursor N | bsum 256 | bpre 256 | act_eid E | rawbuf E | wbuf E | sbuf E | rw2T 4096
    unsigned* ws       = (unsigned*)d_ws;
    unsigned* counters = ws;
    unsigned* segmax   = ws + 4;
    float*    denom    = (float*)(ws + 4 + 1 * (size_t)N);
    unsigned* hist     = ws + 4 + 2 * (size_t)N;
    unsigned* mask     = ws + 4 + 3 * (size_t)N;
    unsigned* mlist    = ws + 4 + 4 * (size_t)N;
    unsigned* offs     = ws + 4 + 5 * (size_t)N;
    unsigned* cursor   = ws + 4 + 6 * (size_t)N + 1;
    unsigned* bsum     = ws + 4 + 7 * (size_t)N + 1;
    unsigned* bpre     = bsum + 256;
    unsigned* act_eid  = bpre + 256;
    float*    rawbuf   = (float*)(act_eid + (size_t)E);
    float*    wbuf     = (float*)(act_eid + 2 * (size_t)E);
    unsigned* sbuf     = act_eid + 3 * (size_t)E;
    float*    rw2T     = (float*)(act_eid + 4 * (size_t)E);

    // zero counters + segmax + denom + hist (contiguous prefix)
    (void)hipMemsetAsync(d_ws, 0, (size_t)(4 + 3 * (size_t)N) * 4, stream);

    k_prep<<<(HID * HID + 255) / 256, 256, 0, stream>>>(rw2, rw2T);
    k_protect<<<(N + 63) / 64, 256, 0, stream>>>(states, caps, pw1, pb1, pw2, pb2,
                                                 mask, mlist, counters, out + (size_t)N * D, N);
    k_nodemlp<<<(N + 63) / 64, 256, 0, stream>>>(states, mask, rw1, uv, N);
    k_compact<<<(E + 255) / 256, 256, 0, stream>>>(ei, mask, act_eid, counters, hist, E);
    k_scanA<<<nb, 256, 0, stream>>>(hist, bsum, N);
    k_scanB<<<1, 256, 0, stream>>>(bsum, bpre, nb);
    k_scanC<<<nb, 256, 0, stream>>>(hist, bpre, offs, cursor, N);
    k_edge_mlp<<<(E + 255) / 256, 256, 0, stream>>>(uv, ei, rb1, rw2T, rb2, rw3, rb3,
                                                    act_eid, counters, rawbuf, segmax, E);
    k_exp<<<(E + 255) / 256, 256, 0, stream>>>(ei, act_eid, counters, segmax, rawbuf, denom, E);
    k_fill<<<(E + 255) / 256, 256, 0, stream>>>(ei, act_eid, counters, rawbuf, denom,
                                                cursor, wbuf, sbuf, E);
    k_gather<<<(N + 3) / 4, 256, 0, stream>>>(states, wbuf, sbuf, offs, mask, out, N);
    k_jump<<<(N + 7) / 8, 256, 0, stream>>>(states, tw, tb, mlist, counters, out);
}

// Round 20
// 266.092 us; speedup vs baseline: 1.0971x; 1.0012x over previous
//
#include <hip/hip_runtime.h>
#include <cmath>

#define D 128
#define HID 64

__device__ __forceinline__ float silu_f(float x) { return x / (1.0f + expf(-x)); }

__device__ __forceinline__ float4 fma4(float a, float4 w, float4 c) {
    c.x = fmaf(a, w.x, c.x); c.y = fmaf(a, w.y, c.y);
    c.z = fmaf(a, w.z, c.z); c.w = fmaf(a, w.w, c.w);
    return c;
}
__device__ __forceinline__ float4 silu4(float4 v) {
    v.x = silu_f(v.x); v.y = silu_f(v.y); v.z = silu_f(v.z); v.w = silu_f(v.w);
    return v;
}

// order-preserving float <-> uint encode for atomicMax on floats
__device__ __forceinline__ unsigned fenc(float f) {
    unsigned u = __float_as_uint(f);
    return (u & 0x80000000u) ? ~u : (u | 0x80000000u);
}
__device__ __forceinline__ float fdec(unsigned e) {
    unsigned u = (e & 0x80000000u) ? (e & 0x7FFFFFFFu) : ~e;
    return __uint_as_float(u);
}

#define INIT16(bp) { const float4* _b4 = reinterpret_cast<const float4*>(bp); \
    h0 = _b4[0]; h1 = _b4[1]; h2 = _b4[2]; h3 = _b4[3]; \
    h4 = _b4[4]; h5 = _b4[5]; h6 = _b4[6]; h7 = _b4[7]; \
    h8 = _b4[8]; h9 = _b4[9]; h10 = _b4[10]; h11 = _b4[11]; \
    h12 = _b4[12]; h13 = _b4[13]; h14 = _b4[14]; h15 = _b4[15]; }

#define SILU16() { h0 = silu4(h0); h1 = silu4(h1); h2 = silu4(h2); h3 = silu4(h3); \
    h4 = silu4(h4); h5 = silu4(h5); h6 = silu4(h6); h7 = silu4(h7); \
    h8 = silu4(h8); h9 = silu4(h9); h10 = silu4(h10); h11 = silu4(h11); \
    h12 = silu4(h12); h13 = silu4(h13); h14 = silu4(h14); h15 = silu4(h15); }

// dot with 4 partial sums, k%4 -> s0..s3
__device__ __forceinline__ void fd4(float4 h, float4 w, float& s0, float& s1, float& s2, float& s3) {
    s0 = fmaf(h.x, w.x, s0); s1 = fmaf(h.y, w.y, s1);
    s2 = fmaf(h.z, w.z, s2); s3 = fmaf(h.w, w.w, s3);
}
#define FD16(w4) { fd4(h0, w4[0], s0, s1, s2, s3);  fd4(h1, w4[1], s0, s1, s2, s3);  \
    fd4(h2, w4[2], s0, s1, s2, s3);  fd4(h3, w4[3], s0, s1, s2, s3);  \
    fd4(h4, w4[4], s0, s1, s2, s3);  fd4(h5, w4[5], s0, s1, s2, s3);  \
    fd4(h6, w4[6], s0, s1, s2, s3);  fd4(h7, w4[7], s0, s1, s2, s3);  \
    fd4(h8, w4[8], s0, s1, s2, s3);  fd4(h9, w4[9], s0, s1, s2, s3);  \
    fd4(h10, w4[10], s0, s1, s2, s3); fd4(h11, w4[11], s0, s1, s2, s3); \
    fd4(h12, w4[12], s0, s1, s2, s3); fd4(h13, w4[13], s0, s1, s2, s3); \
    fd4(h14, w4[14], s0, s1, s2, s3); fd4(h15, w4[15], s0, s1, s2, s3); }

// serial silu-dot over 4 units
__device__ __forceinline__ float accdot(float4 h, float4 w, float act) {
    act = fmaf(silu_f(h.x), w.x, act);
    act = fmaf(silu_f(h.y), w.y, act);
    act = fmaf(silu_f(h.z), w.z, act);
    act = fmaf(silu_f(h.w), w.w, act);
    return act;
}

// transpose rw2 (64x64) -> rw2T[j*64+k] = rw2[k*64+j]  (uniform contiguous rows per j)
__global__ void k_prep(const float* __restrict__ rw2, float* __restrict__ rw2T) {
    int i = blockIdx.x * blockDim.x + threadIdx.x;
    if (i < HID * HID) rw2T[i] = rw2[(i & (HID - 1)) * HID + (i >> 6)];
}

// ---- protection net: 4 lanes/node split-hid, full pw1 in LDS, 64 nodes/block ----
__global__ __launch_bounds__(256) void k_protect(
    const float* __restrict__ states, const float* __restrict__ caps,
    const float* __restrict__ pw1, const float* __restrict__ pb1,
    const float* __restrict__ pw2, const float* __restrict__ pb2,
    unsigned* __restrict__ mask, unsigned* __restrict__ mlist,
    unsigned* __restrict__ counters, float* __restrict__ outmask, int N) {
    __shared__ float wl[129 * 64];                // 33 KB: all of pw1 (incl. capacity row)
    unsigned tid = threadIdx.x;
    {   // stage 8256 floats = 2064 float4, coalesced
        const float4* s4 = reinterpret_cast<const float4*>(pw1);
        float4* d4 = reinterpret_cast<float4*>(wl);
#pragma unroll
        for (int q = 0; q < 9; ++q) {
            unsigned idx = tid + q * 256u;
            if (idx < 2064u) d4[idx] = s4[idx];
        }
    }
    __syncthreads();
    unsigned nl = tid >> 2, g = tid & 3u;         // lane g owns hidden units [g*16, g*16+16)
    unsigned n = blockIdx.x * 64u + nl;
    bool active = n < (unsigned)N;
    unsigned nq = active ? n : (unsigned)(N - 1);
    const float4* row = reinterpret_cast<const float4*>(states + (size_t)nq * D);
    float4 a0, a1, a2, a3;
    { const float4* b4 = reinterpret_cast<const float4*>(pb1 + g * 16);
      a0 = b4[0]; a1 = b4[1]; a2 = b4[2]; a3 = b4[3]; }
    const float* wg = wl + g * 16;
#pragma unroll 4
    for (int kb = 0; kb < 32; ++kb) {
        float4 x = row[kb];
        const float* w = wg + (size_t)kb * 4 * HID;
        const float4* w0 = reinterpret_cast<const float4*>(w);
        const float4* w1 = reinterpret_cast<const float4*>(w + HID);
        const float4* w2q = reinterpret_cast<const float4*>(w + 2 * HID);
        const float4* w3q = reinterpret_cast<const float4*>(w + 3 * HID);
        a0 = fma4(x.x, w0[0], a0); a1 = fma4(x.x, w0[1], a1); a2 = fma4(x.x, w0[2], a2); a3 = fma4(x.x, w0[3], a3);
        a0 = fma4(x.y, w1[0], a0); a1 = fma4(x.y, w1[1], a1); a2 = fma4(x.y, w1[2], a2); a3 = fma4(x.y, w1[3], a3);
        a0 = fma4(x.z, w2q[0], a0); a1 = fma4(x.z, w2q[1], a1); a2 = fma4(x.z, w2q[2], a2); a3 = fma4(x.z, w2q[3], a3);
        a0 = fma4(x.w, w3q[0], a0); a1 = fma4(x.w, w3q[1], a1); a2 = fma4(x.w, w3q[2], a2); a3 = fma4(x.w, w3q[3], a3);
    }
    {   // capacity row (input dim 128)
        float xv = caps[nq];
        const float4* wc = reinterpret_cast<const float4*>(wg + (size_t)128 * HID);
        a0 = fma4(xv, wc[0], a0); a1 = fma4(xv, wc[1], a1);
        a2 = fma4(xv, wc[2], a2); a3 = fma4(xv, wc[3], a3);
    }
    // layer-2 partial over this lane's 16 units, then 4-lane butterfly reduce
    const float4* w2 = reinterpret_cast<const float4*>(pw2 + g * 16);
    float p = 0.0f;
    p = accdot(a0, w2[0], p); p = accdot(a1, w2[1], p);
    p = accdot(a2, w2[2], p); p = accdot(a3, w2[3], p);
    p += __shfl_xor(p, 1);
    p += __shfl_xor(p, 2);
    // mask decision + wave-aggregated append to mlist (one atomic per wave)
    bool pred = false;
    if (active && g == 0) {
        float act = p + pb2[0];
        unsigned m = (act > 0.0f) ? 1u : 0u;
        mask[n] = m;
        outmask[n] = m ? 1.0f : 0.0f;
        pred = (m != 0u);
    }
    unsigned lane = tid & 63u;
    unsigned long long bal = __ballot(pred);
    unsigned wcnt = (unsigned)__popcll(bal);
    unsigned pre  = (unsigned)__popcll(bal & ((1ull << lane) - 1ull));
    unsigned base = 0;
    if (lane == 0 && wcnt) base = atomicAdd(&counters[1], wcnt);
    base = __shfl(base, 0);
    if (pred) mlist[base + pre] = n;
}

// ---- per-node layer-1 factorization: uv[n] = (mask ? W1a : W1b) @ states[n] ----
__global__ __launch_bounds__(256) void k_nodemlp(
    const float* __restrict__ states, const unsigned* __restrict__ mask,
    const float* __restrict__ rw1, float* __restrict__ uv, int N) {
    __shared__ float wl[16384];                   // 64 KB: W1a (8192) | W1b (8192)
    unsigned tid = threadIdx.x;
    {   // stage all of rw1: 4096 float4, coalesced
        const float4* s4 = reinterpret_cast<const float4*>(rw1);
        float4* d4 = reinterpret_cast<float4*>(wl);
#pragma unroll
        for (int q = 0; q < 16; ++q) d4[tid + q * 256u] = s4[tid + q * 256u];
    }
    __syncthreads();
    unsigned nl = tid >> 2, g = tid & 3u;
    unsigned n = blockIdx.x * 64u + nl;
    if (n >= (unsigned)N) return;
    const float4* row = reinterpret_cast<const float4*>(states + (size_t)n * D);
    unsigned m = mask[n];
    const float* wg = wl + (m ? 0u : 8192u) + g * 16;
    float4 a0, a1, a2, a3;
    a0.x=a0.y=a0.z=a0.w=0.f; a1=a0; a2=a0; a3=a0;
#pragma unroll 4
    for (int kb = 0; kb < 32; ++kb) {
        float4 x = row[kb];
        const float* w = wg + (size_t)kb * 4 * HID;
        const float4* w0 = reinterpret_cast<const float4*>(w);
        const float4* w1 = reinterpret_cast<const float4*>(w + HID);
        const float4* w2q = reinterpret_cast<const float4*>(w + 2 * HID);
        const float4* w3q = reinterpret_cast<const float4*>(w + 3 * HID);
        a0 = fma4(x.x, w0[0], a0); a1 = fma4(x.x, w0[1], a1); a2 = fma4(x.x, w0[2], a2); a3 = fma4(x.x, w0[3], a3);
        a0 = fma4(x.y, w1[0], a0); a1 = fma4(x.y, w1[1], a1); a2 = fma4(x.y, w1[2], a2); a3 = fma4(x.y, w1[3], a3);
        a0 = fma4(x.z, w2q[0], a0); a1 = fma4(x.z, w2q[1], a1); a2 = fma4(x.z, w2q[2], a2); a3 = fma4(x.z, w2q[3], a3);
        a0 = fma4(x.w, w3q[0], a0); a1 = fma4(x.w, w3q[1], a1); a2 = fma4(x.w, w3q[2], a2); a3 = fma4(x.w, w3q[3], a3);
    }
    float4* o = reinterpret_cast<float4*>(uv + (size_t)n * HID + g * 16);
    o[0] = a0; o[1] = a1; o[2] = a2; o[3] = a3;
}

// compact edges with emask = mask[src] && !mask[tgt]; block-aggregated slot alloc
__global__ __launch_bounds__(256) void k_compact(
    const int* __restrict__ ei, const unsigned* __restrict__ mask,
    unsigned* __restrict__ act_eid, unsigned* __restrict__ counters,
    unsigned* __restrict__ hist, int E) {
    __shared__ unsigned wbase[4];
    int e = blockIdx.x * 256 + threadIdx.x;
    unsigned wid = threadIdx.x >> 6, lane = threadIdx.x & 63u;
    bool pred = false; int t = 0;
    if (e < E) {
        int s = ei[e]; t = ei[E + e];
        pred = mask[s] && !mask[t];
    }
    unsigned long long bal = __ballot(pred);
    unsigned wcnt = (unsigned)__popcll(bal);
    unsigned pre  = (unsigned)__popcll(bal & ((1ull << lane) - 1ull));
    if (lane == 0) wbase[wid] = wcnt;
    __syncthreads();
    if (threadIdx.x == 0) {
        unsigned c0 = wbase[0], c1 = wbase[1], c2 = wbase[2], c3 = wbase[3];
        unsigned tot = c0 + c1 + c2 + c3;
        unsigned b = tot ? atomicAdd(&counters[0], tot) : 0u;
        wbase[0] = b; wbase[1] = b + c0; wbase[2] = b + c0 + c1; wbase[3] = b + c0 + c1 + c2;
    }
    __syncthreads();
    if (pred) {
        act_eid[wbase[wid] + pre] = (unsigned)e;
        atomicAdd(&hist[t], 1u);
    }
}

// --- hierarchical exclusive scan of hist[N] -> offs[N+1], cursor[N] ---
__global__ __launch_bounds__(256) void k_scanA(const unsigned* __restrict__ hist,
                                               unsigned* __restrict__ bsum, int N) {
    __shared__ unsigned sm[256];
    unsigned t = threadIdx.x;
    unsigned i = blockIdx.x * 256u + t;
    sm[t] = (i < (unsigned)N) ? hist[i] : 0u;
    __syncthreads();
#pragma unroll
    for (unsigned d = 128; d > 0; d >>= 1) {
        if (t < d) sm[t] += sm[t + d];
        __syncthreads();
    }
    if (t == 0) bsum[blockIdx.x] = sm[0];
}
__global__ __launch_bounds__(256) void k_scanB(const unsigned* __restrict__ bsum,
                                               unsigned* __restrict__ bpre, int nb) {
    __shared__ unsigned sm[256];
    unsigned t = threadIdx.x;
    unsigned v = (t < (unsigned)nb) ? bsum[t] : 0u;
    sm[t] = v;
    __syncthreads();
    for (unsigned d = 1; d < 256; d <<= 1) {
        unsigned x = (t >= d) ? sm[t - d] : 0u;
        __syncthreads();
        sm[t] += x;
        __syncthreads();
    }
    if (t < (unsigned)nb) bpre[t] = sm[t] - v;    // exclusive
}
__global__ __launch_bounds__(256) void k_scanC(const unsigned* __restrict__ hist,
                                               const unsigned* __restrict__ bpre,
                                               unsigned* __restrict__ offs,
                                               unsigned* __restrict__ cursor, int N) {
    __shared__ unsigned sm[256];
    unsigned t = threadIdx.x;
    unsigned i = blockIdx.x * 256u + t;
    unsigned v = (i < (unsigned)N) ? hist[i] : 0u;
    sm[t] = v;
    __syncthreads();
    for (unsigned d = 1; d < 256; d <<= 1) {
        unsigned x = (t >= d) ? sm[t - d] : 0u;
        __syncthreads();
        sm[t] += x;
        __syncthreads();
    }
    unsigned exc = sm[t] - v + bpre[blockIdx.x];
    if (i < (unsigned)N) { offs[i] = exc; cursor[i] = exc; }
    if (i == (unsigned)N - 1) offs[N] = exc + v;
}

// ---- edge MLP: h = silu(b1 + uv[src] + uv[tgt]); layers 2+3 from GLOBAL rw2T ----
__global__ __launch_bounds__(256) void k_edge_mlp(
    const float* __restrict__ uv, const int* __restrict__ ei,
    const float* __restrict__ rb1, const float* __restrict__ rw2T,
    const float* __restrict__ rb2, const float* __restrict__ rw3,
    const float* __restrict__ rb3,
    const unsigned* __restrict__ act_eid, const unsigned* __restrict__ counters,
    float* __restrict__ rawbuf, unsigned* __restrict__ segmax, int E) {
    unsigned cnt = counters[0];
    if (blockIdx.x * 256u >= cnt) return;         // whole block inactive (uniform)
    unsigned tid = threadIdx.x;
    unsigned grp = blockIdx.x * 256u + tid;
    bool active = grp < cnt;
    unsigned gq = active ? grp : (cnt - 1);
    int e = (int)act_eid[gq];
    int s = ei[e], tg = ei[E + e];
    const float4* ur = reinterpret_cast<const float4*>(uv + (size_t)s * HID);
    const float4* vr = reinterpret_cast<const float4*>(uv + (size_t)tg * HID);
    float4 h0, h1, h2, h3, h4, h5, h6, h7, h8, h9, h10, h11, h12, h13, h14, h15;
    INIT16(rb1);
#define ADDUV(hh, i) { float4 _u = ur[i]; float4 _v = vr[i]; \
    hh.x = hh.x + _u.x + _v.x; hh.y = hh.y + _u.y + _v.y; \
    hh.z = hh.z + _u.z + _v.z; hh.w = hh.w + _u.w + _v.w; }
    ADDUV(h0, 0)  ADDUV(h1, 1)  ADDUV(h2, 2)  ADDUV(h3, 3)
    ADDUV(h4, 4)  ADDUV(h5, 5)  ADDUV(h6, 6)  ADDUV(h7, 7)
    ADDUV(h8, 8)  ADDUV(h9, 9)  ADDUV(h10, 10) ADDUV(h11, 11)
    ADDUV(h12, 12) ADDUV(h13, 13) ADDUV(h14, 14) ADDUV(h15, 15)
#undef ADDUV
    SILU16();
    // layers 2+3 fused: per j, dot(h, rw2T[j]) -> silu -> raw += h2*rw3[j]
    float raw = rb3[0];
#pragma unroll 1
    for (int j = 0; j < HID; ++j) {
        const float4* w4 = reinterpret_cast<const float4*>(rw2T + (size_t)j * HID);
        float s0 = rb2[j], s1 = 0.f, s2 = 0.f, s3 = 0.f;
        FD16(w4);
        float h2v = silu_f((s0 + s1) + (s2 + s3));
        raw = fmaf(h2v, rw3[j], raw);
    }
    if (active) {
        rawbuf[grp] = raw;
        atomicMax(&segmax[s], fenc(raw));
    }
}

// fused exp + bucket: ev = exp(raw - segmax[s]); denom[s] += ev;
// bucket (undivided) ev + src by target; gather divides by denom later.
__global__ void k_expfill(const int* __restrict__ ei, const unsigned* __restrict__ act_eid,
                          const unsigned* __restrict__ counters, const unsigned* __restrict__ segmax,
                          const float* __restrict__ rawbuf, float* __restrict__ denom,
                          unsigned* __restrict__ cursor,
                          float* __restrict__ wbuf, unsigned* __restrict__ sbuf, int E) {
    unsigned t = blockIdx.x * blockDim.x + threadIdx.x;
    if (blockIdx.x * blockDim.x >= counters[0]) return;
    if (t >= counters[0]) return;
    int e = (int)act_eid[t];
    int s = ei[e], tg = ei[E + e];
    float ev = expf(rawbuf[t] - fdec(segmax[s]));
    atomicAdd(&denom[s], ev);
    unsigned pos = atomicAdd(&cursor[tg], 1u);
    wbuf[pos] = ev;
    sbuf[pos] = (unsigned)s;
}

// wave per node: out[n] = states[n] + sum_{incoming active} (ev/denom[s]) * states[src]
__global__ __launch_bounds__(256) void k_gather(
    const float* __restrict__ states, const float* __restrict__ wbuf,
    const unsigned* __restrict__ sbuf, const unsigned* __restrict__ offs,
    const float* __restrict__ denom, const unsigned* __restrict__ mask,
    float* __restrict__ out, int N) {
    unsigned n = blockIdx.x * 4u + (threadIdx.x >> 6);
    unsigned lane = threadIdx.x & 63u;
    if (n >= (unsigned)N) return;
    if (mask[n]) return;                          // overwritten by k_jump
    unsigned start = offs[n], end = offs[n + 1];
    float2 acc = reinterpret_cast<const float2*>(states + (size_t)n * D)[lane];
    for (unsigned i = start; i < end; ++i) {
        unsigned s = sbuf[i];
        float w = wbuf[i] / denom[s];
        float2 sv = reinterpret_cast<const float2*>(states + (size_t)s * D)[lane];
        acc.x = fmaf(w, sv.x, acc.x);
        acc.y = fmaf(w, sv.y, acc.y);
    }
    reinterpret_cast<float2*>(out + (size_t)n * D)[lane] = acc;
}

// failed nodes: out = tanh(states @ tw + tb) * 0.05
__global__ __launch_bounds__(256) void k_jump(
    const float* __restrict__ states,
    const float* __restrict__ tw, const float* __restrict__ tb,
    const unsigned* __restrict__ mlist, const unsigned* __restrict__ counters,
    float* __restrict__ out) {
    __shared__ float xs[8][D];
    unsigned cnt = counters[1];
    unsigned base = blockIdx.x * 8u;
    if (base >= cnt || cnt == 0) return;          // uniform
    unsigned tid = threadIdx.x;
    unsigned d = tid & 127u, r = tid >> 7;        // r in {0,1}
    {   // stage 8 rows (clamped): 32 threads per row, float4 each
        unsigned j = tid >> 5;
        unsigned c = (tid & 31u) * 4u;
        unsigned slot = base + j; if (slot >= cnt) slot = cnt - 1;
        int nn = (int)mlist[slot];
        *reinterpret_cast<float4*>(&xs[j][c]) =
            *reinterpret_cast<const float4*>(&states[(size_t)nn * D + c]);
    }
    __syncthreads();
    float tbd = tb[d];
    float a0 = tbd, a1 = tbd, a2 = tbd, a3 = tbd;
    const float* x0 = &xs[r * 4 + 0][0];
    const float* x1 = &xs[r * 4 + 1][0];
    const float* x2 = &xs[r * 4 + 2][0];
    const float* x3 = &xs[r * 4 + 3][0];
#pragma unroll 1
    for (int k = 0; k < D; ++k) {
        float w = tw[(size_t)k * D + d];
        a0 = fmaf(x0[k], w, a0);
        a1 = fmaf(x1[k], w, a1);
        a2 = fmaf(x2[k], w, a2);
        a3 = fmaf(x3[k], w, a3);
    }
    float res[4] = {a0, a1, a2, a3};
#pragma unroll
    for (int j2 = 0; j2 < 4; ++j2) {
        unsigned slot = base + r * 4 + j2;
        if (slot < cnt) {
            int nn = (int)mlist[slot];
            out[(size_t)nn * D + d] = tanhf(res[j2]) * 0.05f;
        }
    }
}

extern "C" void kernel_launch(void* const* d_in, const int* in_sizes, int n_in,
                              void* d_out, int out_size, void* d_ws, size_t ws_size,
                              hipStream_t stream) {
    const float* states = (const float*)d_in[0];
    const float* caps   = (const float*)d_in[1];
    const int*   ei     = (const int*)d_in[2];
    const float* rw1 = (const float*)d_in[3];  const float* rb1 = (const float*)d_in[4];
    const float* rw2 = (const float*)d_in[5];  const float* rb2 = (const float*)d_in[6];
    const float* rw3 = (const float*)d_in[7];  const float* rb3 = (const float*)d_in[8];
    const float* pw1 = (const float*)d_in[9];  const float* pb1 = (const float*)d_in[10];
    const float* pw2 = (const float*)d_in[11]; const float* pb2 = (const float*)d_in[12];
    const float* tw  = (const float*)d_in[13]; const float* tb  = (const float*)d_in[14];
    const int N = in_sizes[1];
    const int E = in_sizes[2] / 2;
    float* out = (float*)d_out;
    const int nb = (N + 255) / 256;

    // uv lives in d_out[0 : N*HID) — dead scratch until k_gather/k_jump write out.
    float* uv = out;

    // ws layout (u32 units):
    // [0..3] counters | segmax N | denom N | hist N | mask N | mlist N |
    // offs N+1 | cursor N | bsum 256 | bpre 256 | act_eid E | rawbuf E | wbuf E | sbuf E | rw2T 4096
    unsigned* ws       = (unsigned*)d_ws;
    unsigned* counters = ws;
    unsigned* segmax   = ws + 4;
    float*    denom    = (float*)(ws + 4 + 1 * (size_t)N);
    unsigned* hist     = ws + 4 + 2 * (size_t)N;
    unsigned* mask     = ws + 4 + 3 * (size_t)N;
    unsigned* mlist    = ws + 4 + 4 * (size_t)N;
    unsigned* offs     = ws + 4 + 5 * (size_t)N;
    unsigned* cursor   = ws + 4 + 6 * (size_t)N + 1;
    unsigned* bsum     = ws + 4 + 7 * (size_t)N + 1;
    unsigned* bpre     = bsum + 256;
    unsigned* act_eid  = bpre + 256;
    float*    rawbuf   = (float*)(act_eid + (size_t)E);
    float*    wbuf     = (float*)(act_eid + 2 * (size_t)E);
    unsigned* sbuf     = act_eid + 3 * (size_t)E;
    float*    rw2T     = (float*)(act_eid + 4 * (size_t)E);

    // zero counters + segmax + denom + hist (contiguous prefix)
    (void)hipMemsetAsync(d_ws, 0, (size_t)(4 + 3 * (size_t)N) * 4, stream);

    k_prep<<<(HID * HID + 255) / 256, 256, 0, stream>>>(rw2, rw2T);
    k_protect<<<(N + 63) / 64, 256, 0, stream>>>(states, caps, pw1, pb1, pw2, pb2,
                                                 mask, mlist, counters, out + (size_t)N * D, N);
    k_nodemlp<<<(N + 63) / 64, 256, 0, stream>>>(states, mask, rw1, uv, N);
    k_compact<<<(E + 255) / 256, 256, 0, stream>>>(ei, mask, act_eid, counters, hist, E);
    k_scanA<<<nb, 256, 0, stream>>>(hist, bsum, N);
    k_scanB<<<1, 256, 0, stream>>>(bsum, bpre, nb);
    k_scanC<<<nb, 256, 0, stream>>>(hist, bpre, offs, cursor, N);
    k_edge_mlp<<<(E + 255) / 256, 256, 0, stream>>>(uv, ei, rb1, rw2T, rb2, rw3, rb3,
                                                    act_eid, counters, rawbuf, segmax, E);
    k_expfill<<<(E + 255) / 256, 256, 0, stream>>>(ei, act_eid, counters, segmax, rawbuf,
                                                   denom, cursor, wbuf, sbuf, E);
    k_gather<<<(N + 3) / 4, 256, 0, stream>>>(states, wbuf, sbuf, offs, denom, mask, out, N);
    k_jump<<<(N + 7) / 8, 256, 0, stream>>>(states, tw, tb, mlist, counters, out);
}

// Round 21
// 256.550 us; speedup vs baseline: 1.1379x; 1.0372x over previous
//
#include <hip/hip_runtime.h>
#include <cmath>

#define D 128
#define HID 64

__device__ __forceinline__ float silu_f(float x) { return x / (1.0f + expf(-x)); }

__device__ __forceinline__ float4 fma4(float a, float4 w, float4 c) {
    c.x = fmaf(a, w.x, c.x); c.y = fmaf(a, w.y, c.y);
    c.z = fmaf(a, w.z, c.z); c.w = fmaf(a, w.w, c.w);
    return c;
}
__device__ __forceinline__ float4 silu4(float4 v) {
    v.x = silu_f(v.x); v.y = silu_f(v.y); v.z = silu_f(v.z); v.w = silu_f(v.w);
    return v;
}

#define INIT16(bp) { const float4* _b4 = reinterpret_cast<const float4*>(bp); \
    h0 = _b4[0]; h1 = _b4[1]; h2 = _b4[2]; h3 = _b4[3]; \
    h4 = _b4[4]; h5 = _b4[5]; h6 = _b4[6]; h7 = _b4[7]; \
    h8 = _b4[8]; h9 = _b4[9]; h10 = _b4[10]; h11 = _b4[11]; \
    h12 = _b4[12]; h13 = _b4[13]; h14 = _b4[14]; h15 = _b4[15]; }

#define SILU16() { h0 = silu4(h0); h1 = silu4(h1); h2 = silu4(h2); h3 = silu4(h3); \
    h4 = silu4(h4); h5 = silu4(h5); h6 = silu4(h6); h7 = silu4(h7); \
    h8 = silu4(h8); h9 = silu4(h9); h10 = silu4(h10); h11 = silu4(h11); \
    h12 = silu4(h12); h13 = silu4(h13); h14 = silu4(h14); h15 = silu4(h15); }

// dot with 4 partial sums, k%4 -> s0..s3
__device__ __forceinline__ void fd4(float4 h, float4 w, float& s0, float& s1, float& s2, float& s3) {
    s0 = fmaf(h.x, w.x, s0); s1 = fmaf(h.y, w.y, s1);
    s2 = fmaf(h.z, w.z, s2); s3 = fmaf(h.w, w.w, s3);
}
#define FD16(w4) { fd4(h0, w4[0], s0, s1, s2, s3);  fd4(h1, w4[1], s0, s1, s2, s3);  \
    fd4(h2, w4[2], s0, s1, s2, s3);  fd4(h3, w4[3], s0, s1, s2, s3);  \
    fd4(h4, w4[4], s0, s1, s2, s3);  fd4(h5, w4[5], s0, s1, s2, s3);  \
    fd4(h6, w4[6], s0, s1, s2, s3);  fd4(h7, w4[7], s0, s1, s2, s3);  \
    fd4(h8, w4[8], s0, s1, s2, s3);  fd4(h9, w4[9], s0, s1, s2, s3);  \
    fd4(h10, w4[10], s0, s1, s2, s3); fd4(h11, w4[11], s0, s1, s2, s3); \
    fd4(h12, w4[12], s0, s1, s2, s3); fd4(h13, w4[13], s0, s1, s2, s3); \
    fd4(h14, w4[14], s0, s1, s2, s3); fd4(h15, w4[15], s0, s1, s2, s3); }

// serial silu-dot over 4 units
__device__ __forceinline__ float accdot(float4 h, float4 w, float act) {
    act = fmaf(silu_f(h.x), w.x, act);
    act = fmaf(silu_f(h.y), w.y, act);
    act = fmaf(silu_f(h.z), w.z, act);
    act = fmaf(silu_f(h.w), w.w, act);
    return act;
}

// transpose rw2 (64x64) -> rw2T[j*64+k] = rw2[k*64+j]
__global__ void k_prep(const float* __restrict__ rw2, float* __restrict__ rw2T) {
    int i = blockIdx.x * blockDim.x + threadIdx.x;
    if (i < HID * HID) rw2T[i] = rw2[(i & (HID - 1)) * HID + (i >> 6)];
}

// ---- FUSED: protection net + per-node layer-1 uv; 4 lanes/node, 64 nodes/block ----
// phase 1: pw1 in LDS -> mask (kept in-register); phase 2: rw1 in LDS -> uv.
__global__ __launch_bounds__(256) void k_node(
    const float* __restrict__ states, const float* __restrict__ caps,
    const float* __restrict__ pw1, const float* __restrict__ pb1,
    const float* __restrict__ pw2, const float* __restrict__ pb2,
    const float* __restrict__ rw1,
    unsigned* __restrict__ mask, unsigned* __restrict__ mlist,
    unsigned* __restrict__ counters, float* __restrict__ outmask,
    float* __restrict__ uv, int N) {
    __shared__ float wl[16384];                   // 64 KB, reused across phases
    unsigned tid = threadIdx.x;
    {   // stage pw1: 2064 float4, coalesced
        const float4* s4 = reinterpret_cast<const float4*>(pw1);
        float4* d4 = reinterpret_cast<float4*>(wl);
#pragma unroll
        for (int q = 0; q < 9; ++q) {
            unsigned idx = tid + q * 256u;
            if (idx < 2064u) d4[idx] = s4[idx];
        }
    }
    __syncthreads();
    unsigned nl = tid >> 2, g = tid & 3u;         // lane g owns hidden units [g*16, g*16+16)
    unsigned n = blockIdx.x * 64u + nl;
    bool active = n < (unsigned)N;
    unsigned nq = active ? n : (unsigned)(N - 1);
    const float4* row = reinterpret_cast<const float4*>(states + (size_t)nq * D);
    unsigned m;
    {
        float4 a0, a1, a2, a3;
        { const float4* b4 = reinterpret_cast<const float4*>(pb1 + g * 16);
          a0 = b4[0]; a1 = b4[1]; a2 = b4[2]; a3 = b4[3]; }
        const float* wg = wl + g * 16;
#pragma unroll 4
        for (int kb = 0; kb < 32; ++kb) {
            float4 x = row[kb];
            const float* w = wg + (size_t)kb * 4 * HID;
            const float4* w0 = reinterpret_cast<const float4*>(w);
            const float4* w1 = reinterpret_cast<const float4*>(w + HID);
            const float4* w2q = reinterpret_cast<const float4*>(w + 2 * HID);
            const float4* w3q = reinterpret_cast<const float4*>(w + 3 * HID);
            a0 = fma4(x.x, w0[0], a0); a1 = fma4(x.x, w0[1], a1); a2 = fma4(x.x, w0[2], a2); a3 = fma4(x.x, w0[3], a3);
            a0 = fma4(x.y, w1[0], a0); a1 = fma4(x.y, w1[1], a1); a2 = fma4(x.y, w1[2], a2); a3 = fma4(x.y, w1[3], a3);
            a0 = fma4(x.z, w2q[0], a0); a1 = fma4(x.z, w2q[1], a1); a2 = fma4(x.z, w2q[2], a2); a3 = fma4(x.z, w2q[3], a3);
            a0 = fma4(x.w, w3q[0], a0); a1 = fma4(x.w, w3q[1], a1); a2 = fma4(x.w, w3q[2], a2); a3 = fma4(x.w, w3q[3], a3);
        }
        {   // capacity row (input dim 128)
            float xv = caps[nq];
            const float4* wc = reinterpret_cast<const float4*>(wg + (size_t)128 * HID);
            a0 = fma4(xv, wc[0], a0); a1 = fma4(xv, wc[1], a1);
            a2 = fma4(xv, wc[2], a2); a3 = fma4(xv, wc[3], a3);
        }
        // layer-2 partial over this lane's 16 units, then 4-lane butterfly reduce
        const float4* w2 = reinterpret_cast<const float4*>(pw2 + g * 16);
        float p = 0.0f;
        p = accdot(a0, w2[0], p); p = accdot(a1, w2[1], p);
        p = accdot(a2, w2[2], p); p = accdot(a3, w2[3], p);
        p += __shfl_xor(p, 1);
        p += __shfl_xor(p, 2);                    // all 4 lanes: full (identical) sum
        float act = p + pb2[0];
        m = (act > 0.0f) ? 1u : 0u;
        bool pred = false;
        if (active && g == 0) {
            mask[n] = m;
            outmask[n] = m ? 1.0f : 0.0f;
            pred = (m != 0u);
        }
        unsigned lane = tid & 63u;
        unsigned long long bal = __ballot(pred);
        unsigned wcnt = (unsigned)__popcll(bal);
        unsigned pre  = (unsigned)__popcll(bal & ((1ull << lane) - 1ull));
        unsigned base = 0;
        if (lane == 0 && wcnt) base = atomicAdd(&counters[1], wcnt);
        base = __shfl(base, 0);
        if (pred) mlist[base + pre] = n;
    }
    __syncthreads();                              // all reads of pw1 done
    {   // stage rw1: 4096 float4, coalesced
        const float4* s4 = reinterpret_cast<const float4*>(rw1);
        float4* d4 = reinterpret_cast<float4*>(wl);
#pragma unroll
        for (int q = 0; q < 16; ++q) d4[tid + q * 256u] = s4[tid + q * 256u];
    }
    __syncthreads();
    if (!active) return;
    // uv[n] = (m ? W1a : W1b) @ states[n]
    const float* wg = wl + (m ? 0u : 8192u) + g * 16;
    float4 a0, a1, a2, a3;
    a0.x=a0.y=a0.z=a0.w=0.f; a1=a0; a2=a0; a3=a0;
#pragma unroll 4
    for (int kb = 0; kb < 32; ++kb) {
        float4 x = row[kb];
        const float* w = wg + (size_t)kb * 4 * HID;
        const float4* w0 = reinterpret_cast<const float4*>(w);
        const float4* w1 = reinterpret_cast<const float4*>(w + HID);
        const float4* w2q = reinterpret_cast<const float4*>(w + 2 * HID);
        const float4* w3q = reinterpret_cast<const float4*>(w + 3 * HID);
        a0 = fma4(x.x, w0[0], a0); a1 = fma4(x.x, w0[1], a1); a2 = fma4(x.x, w0[2], a2); a3 = fma4(x.x, w0[3], a3);
        a0 = fma4(x.y, w1[0], a0); a1 = fma4(x.y, w1[1], a1); a2 = fma4(x.y, w1[2], a2); a3 = fma4(x.y, w1[3], a3);
        a0 = fma4(x.z, w2q[0], a0); a1 = fma4(x.z, w2q[1], a1); a2 = fma4(x.z, w2q[2], a2); a3 = fma4(x.z, w2q[3], a3);
        a0 = fma4(x.w, w3q[0], a0); a1 = fma4(x.w, w3q[1], a1); a2 = fma4(x.w, w3q[2], a2); a3 = fma4(x.w, w3q[3], a3);
    }
    float4* o = reinterpret_cast<float4*>(uv + (size_t)n * HID + g * 16);
    o[0] = a0; o[1] = a1; o[2] = a2; o[3] = a3;
}

// compact edges with emask = mask[src] && !mask[tgt]; block-aggregated slot alloc
__global__ __launch_bounds__(256) void k_compact(
    const int* __restrict__ ei, const unsigned* __restrict__ mask,
    unsigned* __restrict__ act_eid, unsigned* __restrict__ counters,
    unsigned* __restrict__ hist, int E) {
    __shared__ unsigned wbase[4];
    int e = blockIdx.x * 256 + threadIdx.x;
    unsigned wid = threadIdx.x >> 6, lane = threadIdx.x & 63u;
    bool pred = false; int t = 0;
    if (e < E) {
        int s = ei[e]; t = ei[E + e];
        pred = mask[s] && !mask[t];
    }
    unsigned long long bal = __ballot(pred);
    unsigned wcnt = (unsigned)__popcll(bal);
    unsigned pre  = (unsigned)__popcll(bal & ((1ull << lane) - 1ull));
    if (lane == 0) wbase[wid] = wcnt;
    __syncthreads();
    if (threadIdx.x == 0) {
        unsigned c0 = wbase[0], c1 = wbase[1], c2 = wbase[2], c3 = wbase[3];
        unsigned tot = c0 + c1 + c2 + c3;
        unsigned b = tot ? atomicAdd(&counters[0], tot) : 0u;
        wbase[0] = b; wbase[1] = b + c0; wbase[2] = b + c0 + c1; wbase[3] = b + c0 + c1 + c2;
    }
    __syncthreads();
    if (pred) {
        act_eid[wbase[wid] + pre] = (unsigned)e;
        atomicAdd(&hist[t], 1u);
    }
}

// --- hierarchical exclusive scan of hist[N] -> offs[N+1], cursor[N] ---
__global__ __launch_bounds__(256) void k_scanA(const unsigned* __restrict__ hist,
                                               unsigned* __restrict__ bsum, int N) {
    __shared__ unsigned sm[256];
    unsigned t = threadIdx.x;
    unsigned i = blockIdx.x * 256u + t;
    sm[t] = (i < (unsigned)N) ? hist[i] : 0u;
    __syncthreads();
#pragma unroll
    for (unsigned d = 128; d > 0; d >>= 1) {
        if (t < d) sm[t] += sm[t + d];
        __syncthreads();
    }
    if (t == 0) bsum[blockIdx.x] = sm[0];
}
__global__ __launch_bounds__(256) void k_scanB(const unsigned* __restrict__ bsum,
                                               unsigned* __restrict__ bpre, int nb) {
    __shared__ unsigned sm[256];
    unsigned t = threadIdx.x;
    unsigned v = (t < (unsigned)nb) ? bsum[t] : 0u;
    sm[t] = v;
    __syncthreads();
    for (unsigned d = 1; d < 256; d <<= 1) {
        unsigned x = (t >= d) ? sm[t - d] : 0u;
        __syncthreads();
        sm[t] += x;
        __syncthreads();
    }
    if (t < (unsigned)nb) bpre[t] = sm[t] - v;    // exclusive
}
__global__ __launch_bounds__(256) void k_scanC(const unsigned* __restrict__ hist,
                                               const unsigned* __restrict__ bpre,
                                               unsigned* __restrict__ offs,
                                               unsigned* __restrict__ cursor, int N) {
    __shared__ unsigned sm[256];
    unsigned t = threadIdx.x;
    unsigned i = blockIdx.x * 256u + t;
    unsigned v = (i < (unsigned)N) ? hist[i] : 0u;
    sm[t] = v;
    __syncthreads();
    for (unsigned d = 1; d < 256; d <<= 1) {
        unsigned x = (t >= d) ? sm[t - d] : 0u;
        __syncthreads();
        sm[t] += x;
        __syncthreads();
    }
    unsigned exc = sm[t] - v + bpre[blockIdx.x];
    if (i < (unsigned)N) { offs[i] = exc; cursor[i] = exc; }
    if (i == (unsigned)N - 1) offs[N] = exc + v;
}

// ---- edge MLP + exp + bucket (no max-shift: softmax is shift-invariant; raw is O(1)) ----
__global__ __launch_bounds__(256) void k_edge_mlp(
    const float* __restrict__ uv, const int* __restrict__ ei,
    const float* __restrict__ rb1, const float* __restrict__ rw2T,
    const float* __restrict__ rb2, const float* __restrict__ rw3,
    const float* __restrict__ rb3,
    const unsigned* __restrict__ act_eid, const unsigned* __restrict__ counters,
    float* __restrict__ denom, unsigned* __restrict__ cursor,
    float* __restrict__ wbuf, unsigned* __restrict__ sbuf, int E) {
    unsigned cnt = counters[0];
    if (blockIdx.x * 256u >= cnt) return;         // whole block inactive (uniform)
    unsigned tid = threadIdx.x;
    unsigned grp = blockIdx.x * 256u + tid;
    bool active = grp < cnt;
    unsigned gq = active ? grp : (cnt - 1);
    int e = (int)act_eid[gq];
    int s = ei[e], tg = ei[E + e];
    const float4* ur = reinterpret_cast<const float4*>(uv + (size_t)s * HID);
    const float4* vr = reinterpret_cast<const float4*>(uv + (size_t)tg * HID);
    float4 h0, h1, h2, h3, h4, h5, h6, h7, h8, h9, h10, h11, h12, h13, h14, h15;
    INIT16(rb1);
#define ADDUV(hh, i) { float4 _u = ur[i]; float4 _v = vr[i]; \
    hh.x = hh.x + _u.x + _v.x; hh.y = hh.y + _u.y + _v.y; \
    hh.z = hh.z + _u.z + _v.z; hh.w = hh.w + _u.w + _v.w; }
    ADDUV(h0, 0)  ADDUV(h1, 1)  ADDUV(h2, 2)  ADDUV(h3, 3)
    ADDUV(h4, 4)  ADDUV(h5, 5)  ADDUV(h6, 6)  ADDUV(h7, 7)
    ADDUV(h8, 8)  ADDUV(h9, 9)  ADDUV(h10, 10) ADDUV(h11, 11)
    ADDUV(h12, 12) ADDUV(h13, 13) ADDUV(h14, 14) ADDUV(h15, 15)
#undef ADDUV
    SILU16();
    // layers 2+3 fused: per j, dot(h, rw2T[j]) -> silu -> raw += h2*rw3[j]
    float raw = rb3[0];
#pragma unroll 1
    for (int j = 0; j < HID; ++j) {
        const float4* w4 = reinterpret_cast<const float4*>(rw2T + (size_t)j * HID);
        float s0 = rb2[j], s1 = 0.f, s2 = 0.f, s3 = 0.f;
        FD16(w4);
        float h2v = silu_f((s0 + s1) + (s2 + s3));
        raw = fmaf(h2v, rw3[j], raw);
    }
    if (active) {
        float ev = expf(raw);
        atomicAdd(&denom[s], ev);
        unsigned pos = atomicAdd(&cursor[tg], 1u);
        wbuf[pos] = ev;
        sbuf[pos] = (unsigned)s;
    }
}

// wave per node: out[n] = states[n] + sum_{incoming active} (ev/denom[s]) * states[src]
__global__ __launch_bounds__(256) void k_gather(
    const float* __restrict__ states, const float* __restrict__ wbuf,
    const unsigned* __restrict__ sbuf, const unsigned* __restrict__ offs,
    const float* __restrict__ denom, const unsigned* __restrict__ mask,
    float* __restrict__ out, int N) {
    unsigned n = blockIdx.x * 4u + (threadIdx.x >> 6);
    unsigned lane = threadIdx.x & 63u;
    if (n >= (unsigned)N) return;
    if (mask[n]) return;                          // overwritten by k_jump
    unsigned start = offs[n], end = offs[n + 1];
    float2 acc = reinterpret_cast<const float2*>(states + (size_t)n * D)[lane];
    for (unsigned i = start; i < end; ++i) {
        unsigned s = sbuf[i];
        float w = wbuf[i] / denom[s];
        float2 sv = reinterpret_cast<const float2*>(states + (size_t)s * D)[lane];
        acc.x = fmaf(w, sv.x, acc.x);
        acc.y = fmaf(w, sv.y, acc.y);
    }
    reinterpret_cast<float2*>(out + (size_t)n * D)[lane] = acc;
}

// failed nodes: out = tanh(states @ tw + tb) * 0.05
__global__ __launch_bounds__(256) void k_jump(
    const float* __restrict__ states,
    const float* __restrict__ tw, const float* __restrict__ tb,
    const unsigned* __restrict__ mlist, const unsigned* __restrict__ counters,
    float* __restrict__ out) {
    __shared__ float xs[8][D];
    unsigned cnt = counters[1];
    unsigned base = blockIdx.x * 8u;
    if (base >= cnt || cnt == 0) return;          // uniform
    unsigned tid = threadIdx.x;
    unsigned d = tid & 127u, r = tid >> 7;        // r in {0,1}
    {   // stage 8 rows (clamped): 32 threads per row, float4 each
        unsigned j = tid >> 5;
        unsigned c = (tid & 31u) * 4u;
        unsigned slot = base + j; if (slot >= cnt) slot = cnt - 1;
        int nn = (int)mlist[slot];
        *reinterpret_cast<float4*>(&xs[j][c]) =
            *reinterpret_cast<const float4*>(&states[(size_t)nn * D + c]);
    }
    __syncthreads();
    float tbd = tb[d];
    float a0 = tbd, a1 = tbd, a2 = tbd, a3 = tbd;
    const float* x0 = &xs[r * 4 + 0][0];
    const float* x1 = &xs[r * 4 + 1][0];
    const float* x2 = &xs[r * 4 + 2][0];
    const float* x3 = &xs[r * 4 + 3][0];
#pragma unroll 1
    for (int k = 0; k < D; ++k) {
        float w = tw[(size_t)k * D + d];
        a0 = fmaf(x0[k], w, a0);
        a1 = fmaf(x1[k], w, a1);
        a2 = fmaf(x2[k], w, a2);
        a3 = fmaf(x3[k], w, a3);
    }
    float res[4] = {a0, a1, a2, a3};
#pragma unroll
    for (int j2 = 0; j2 < 4; ++j2) {
        unsigned slot = base + r * 4 + j2;
        if (slot < cnt) {
            int nn = (int)mlist[slot];
            out[(size_t)nn * D + d] = tanhf(res[j2]) * 0.05f;
        }
    }
}

extern "C" void kernel_launch(void* const* d_in, const int* in_sizes, int n_in,
                              void* d_out, int out_size, void* d_ws, size_t ws_size,
                              hipStream_t stream) {
    const float* states = (const float*)d_in[0];
    const float* caps   = (const float*)d_in[1];
    const int*   ei     = (const int*)d_in[2];
    const float* rw1 = (const float*)d_in[3];  const float* rb1 = (const float*)d_in[4];
    const float* rw2 = (const float*)d_in[5];  const float* rb2 = (const float*)d_in[6];
    const float* rw3 = (const float*)d_in[7];  const float* rb3 = (const float*)d_in[8];
    const float* pw1 = (const float*)d_in[9];  const float* pb1 = (const float*)d_in[10];
    const float* pw2 = (const float*)d_in[11]; const float* pb2 = (const float*)d_in[12];
    const float* tw  = (const float*)d_in[13]; const float* tb  = (const float*)d_in[14];
    const int N = in_sizes[1];
    const int E = in_sizes[2] / 2;
    float* out = (float*)d_out;
    const int nb = (N + 255) / 256;

    // uv lives in d_out[0 : N*HID) — dead scratch until k_gather/k_jump write out.
    float* uv = out;

    // ws layout (u32 units):
    // [0..3] counters | denom N | hist N | mask N | mlist N |
    // offs N+1 | cursor N | bsum 256 | bpre 256 | act_eid E | wbuf E | sbuf E | rw2T 4096
    unsigned* ws       = (unsigned*)d_ws;
    unsigned* counters = ws;
    float*    denom    = (float*)(ws + 4);
    unsigned* hist     = ws + 4 + 1 * (size_t)N;
    unsigned* mask     = ws + 4 + 2 * (size_t)N;
    unsigned* mlist    = ws + 4 + 3 * (size_t)N;
    unsigned* offs     = ws + 4 + 4 * (size_t)N;
    unsigned* cursor   = ws + 4 + 5 * (size_t)N + 1;
    unsigned* bsum     = ws + 4 + 6 * (size_t)N + 1;
    unsigned* bpre     = bsum + 256;
    unsigned* act_eid  = bpre + 256;
    float*    wbuf     = (float*)(act_eid + (size_t)E);
    unsigned* sbuf     = act_eid + 2 * (size_t)E;
    float*    rw2T     = (float*)(act_eid + 3 * (size_t)E);

    // zero counters + denom + hist (contiguous prefix)
    (void)hipMemsetAsync(d_ws, 0, (size_t)(4 + 2 * (size_t)N) * 4, stream);

    k_prep<<<(HID * HID + 255) / 256, 256, 0, stream>>>(rw2, rw2T);
    k_node<<<(N + 63) / 64, 256, 0, stream>>>(states, caps, pw1, pb1, pw2, pb2, rw1,
                                              mask, mlist, counters, out + (size_t)N * D, uv, N);
    k_compact<<<(E + 255) / 256, 256, 0, stream>>>(ei, mask, act_eid, counters, hist, E);
    k_scanA<<<nb, 256, 0, stream>>>(hist, bsum, N);
    k_scanB<<<1, 256, 0, stream>>>(bsum, bpre, nb);
    k_scanC<<<nb, 256, 0, stream>>>(hist, bpre, offs, cursor, N);
    k_edge_mlp<<<(E + 255) / 256, 256, 0, stream>>>(uv, ei, rb1, rw2T, rb2, rw3, rb3,
                                                    act_eid, counters, denom, cursor,
                                                    wbuf, sbuf, E);
    k_gather<<<(N + 3) / 4, 256, 0, stream>>>(states, wbuf, sbuf, offs, denom, mask, out, N);
    k_jump<<<(N + 7) / 8, 256, 0, stream>>>(states, tw, tb, mlist, counters, out);
}